// Round 12
// baseline (2396.126 us; speedup 1.0000x reference)
//
#include <hip/hip_runtime.h>

#define NB 1024
#define HH 256
#define ZS 128
#define PP 16
#define SAMPLE_DIST 0.03125f

typedef __attribute__((ext_vector_type(8))) _Float16 half8v;
typedef __attribute__((ext_vector_type(4))) float f32x4;

struct ZInit { int on; const float* loA; const float* hiA; float lo0,hi0,lo1,hi1; };

__device__ __forceinline__ float sigm(float x){ return 1.0f/(1.0f+__expf(-x)); }

// async global->LDS, 16B per lane; lds dest wave-uniform base (+lane*16 by HW)
__device__ __forceinline__ void gload_lds16(const void* g, void* l){
  __builtin_amdgcn_global_load_lds(
      (const __attribute__((address_space(1))) unsigned int*)g,
      (__attribute__((address_space(3))) unsigned int*)l, 16, 0, 0);
}

__device__ __forceinline__ float iscan_prod(float v, int lane){
  #pragma unroll
  for (int o=1;o<64;o<<=1){ float u=__shfl_up(v,o); if(lane>=o) v*=u; }
  return v;
}
__device__ __forceinline__ float iscan_sum(float v, int lane){
  #pragma unroll
  for (int o=1;o<64;o<<=1){ float u=__shfl_up(v,o); if(lane>=o) v+=u; }
  return v;
}
__device__ __forceinline__ float wave_sum(float v){
  #pragma unroll
  for (int o=1;o<64;o<<=1) v += __shfl_xor(v,o);
  return v;
}

// point loader with optional analytic z-init (sdf kernels, main rays)
__device__ __forceinline__ void load_point2(const float* __restrict__ o, const float* __restrict__ dv,
    const float* __restrict__ z, int idx, int S, int midflag, int zst, ZInit zi, float* pt, float* dir)
{
  int r = idx / S;
  int i = idx - r*S;
  float zz;
  if (zi.on){
    float a=zi.loA[r], b=zi.hiA[r];
    zz = a + (b-a)*((float)i/(float)(S-1));
    if (midflag){
      float z1 = a + (b-a)*((float)(i+1)/(float)(S-1));
      zz = (i < S-1) ? 0.5f*(zz+z1) : (zz + 0.5f*SAMPLE_DIST);
    }
  } else {
    const float* zr = z + r*zst;
    zz = zr[i];
    if (midflag) zz = (i < S-1) ? 0.5f*(zz + zr[i+1]) : (zz + 0.5f*SAMPLE_DIST);
  }
  #pragma unroll
  for (int c=0;c<3;c++){
    float dc = dv[r*3+c];
    pt[c] = o[r*3+c] + dc*zz;
    if (dir) dir[c] = dc;
  }
}

// legacy loader (mask kernel)
__device__ __forceinline__ void load_point(const float* __restrict__ o, const float* __restrict__ dv,
    const float* __restrict__ z, int idx, int S, int midflag, float* pt, float* dir)
{
  int r = idx / S;
  int i = idx - r*S;
  const float* zr = z + r*ZS;
  float zz = zr[i];
  if (midflag) zz = (i < S-1) ? 0.5f*(zz + zr[i+1]) : (zz + 0.5f*SAMPLE_DIST);
  #pragma unroll
  for (int c=0;c<3;c++){
    float dc = dv[r*3+c];
    pt[c] = o[r*3+c] + dc*zz;
    if (dir) dir[c] = dc;
  }
}

// --------- prep: transpose W_sdf1, extract col0 of W_sdf2 ---------
__global__ __launch_bounds__(256) void prep_kernel(const float* __restrict__ W1, const float* __restrict__ W2,
    float* __restrict__ W1T, float* __restrict__ w2col)
{
  int idx = blockIdx.x*256 + threadIdx.x;
  int j = idx >> 8, k = idx & 255;
  W1T[j*HH + k] = W1[k*HH + j];
  if (idx < HH) w2col[idx] = W2[idx*257];
}

// --------- prep: pack 256x256 f32 weight into f16 MFMA B-fragment order ---------
__global__ __launch_bounds__(256) void prep_bfrag_kernel(const float* __restrict__ W1,
    short* __restrict__ Bh)
{
  int idx = blockIdx.x*256 + threadIdx.x;
  int j = idx & 7;
  int lane = (idx>>3) & 63;
  int s = (idx>>9) & 7;
  int nt = idx >> 12;
  int k = s*32 + ((lane>>4)<<3) + j;
  int n = nt*16 + (lane&15);
  union { _Float16 h; short s; } u;
  u.h = (_Float16)W1[k*256 + n];
  Bh[idx] = u.s;
}

// --------- ray table build: 4096 virtual rays ---------
__global__ void build_rays_kernel(const float* __restrict__ ro, const float* __restrict__ rd,
    const float* __restrict__ nearA, const float* __restrict__ farA,
    const float* __restrict__ hit, const float* __restrict__ refl, const float* __restrict__ refr,
    float* __restrict__ rO, float* __restrict__ rD, float* __restrict__ rLo, float* __restrict__ rHi)
{
  int r = blockIdx.x*256 + threadIdx.x;
  if (r >= 4096) return;
  int m = r>>10, q = r&1023;
  const float* so; const float* sd; float lo,hi;
  if (m==0){ so=ro+q*3; sd=rd+q*3; lo=nearA[q]; hi=farA[q]; }
  else if (m==1){ so=hit+q*3; sd=refl+q*3; lo=0.05f; hi=3.7f; }
  else if (m==2){ so=hit+q*3; sd=refr+q*3; lo=0.f; hi=3.7f; }
  else { so=hit+q*3; sd=refr+q*3; lo=0.5f; hi=3.7f; }
  rO[r*3]=so[0]; rO[r*3+1]=so[1]; rO[r*3+2]=so[2];
  rD[r*3]=sd[0]; rD[r*3+1]=sd[1]; rD[r*3+2]=sd[2];
  rLo[r]=lo; rHi[r]=hi;
}

// --------- SDF value MLP: persistent full-B-LDS f16 MFMA ---------
__global__ __launch_bounds__(1024,4) void sdf_mfma_persist(
    const float* __restrict__ o, const float* __restrict__ dv, const float* __restrict__ z,
    int S, int midflag, int zst, ZInit zi, int tilesTotal,
    const float* __restrict__ W0, const float* __restrict__ b0,
    const short* __restrict__ Bh, const float* __restrict__ b1,
    const float* __restrict__ w2col, const float* __restrict__ b2,
    float* __restrict__ out_sdf, unsigned short* __restrict__ signs)
{
  __shared__ short ldsB[65536];
  __shared__ float w0s[3*HH];
  __shared__ float b0s[HH];
  int t=threadIdx.x, wid=t>>6, lane=t&63, g=lane>>4, c16=lane&15;
  for (int i=t;i<3*HH;i+=1024) w0s[i]=W0[i];
  if (t<HH) b0s[t]=b0[t];
  {
    const char* gb=(const char*)Bh;
    #pragma unroll
    for (int c=0;c<8;c++){
      int ch=wid*8+c;
      gload_lds16(gb+ch*1024+lane*16,(void*)&ldsB[ch*512]);
    }
  }
  __syncthreads();
  for (int tile=blockIdx.x*16+wid; tile<tilesTotal; tile+=gridDim.x*16){
    int base=tile*32;
    float xv[2][3];
    #pragma unroll
    for (int mt=0;mt<2;mt++){
      float pt[3];
      load_point2(o,dv,z,base+mt*16+c16,S,midflag,zst,zi,pt,nullptr);
      xv[mt][0]=pt[0]; xv[mt][1]=pt[1]; xv[mt][2]=pt[2];
    }
    half8v af[2][8];
    #pragma unroll
    for (int mt=0;mt<2;mt++){
      float x0=xv[mt][0],x1=xv[mt][1],x2=xv[mt][2];
      #pragma unroll
      for (int s8=0;s8<8;s8++){
        int nb = s8*32 + g*8;
        union { _Float16 h[8]; half8v v; } uh;
        #pragma unroll
        for (int j=0;j<8;j++){
          int n=nb+j;
          float a=b0s[n];
          a=fmaf(x0,w0s[n],a);
          a=fmaf(x1,w0s[HH+n],a);
          a=fmaf(x2,w0s[2*HH+n],a);
          uh.h[j]=(_Float16)fmaxf(a,0.f);
        }
        af[mt][s8]=uh.v;
      }
    }
    float pacc[2][4];
    #pragma unroll
    for (int mt=0;mt<2;mt++){ pacc[mt][0]=0.f; pacc[mt][1]=0.f; pacc[mt][2]=0.f; pacc[mt][3]=0.f; }
    for (int nt=0;nt<16;nt++){
      const short* Lb=&ldsB[nt*4096];
      f32x4 aH[2];
      aH[0]=(f32x4){0.f,0.f,0.f,0.f}; aH[1]=(f32x4){0.f,0.f,0.f,0.f};
      #pragma unroll
      for (int s8=0;s8<8;s8++){
        half8v bh = *(const half8v*)(Lb + s8*512 + lane*8);
        aH[0]=__builtin_amdgcn_mfma_f32_16x16x32_f16(af[0][s8],bh,aH[0],0,0,0);
        aH[1]=__builtin_amdgcn_mfma_f32_16x16x32_f16(af[1][s8],bh,aH[1],0,0,0);
      }
      int n=nt*16+c16;
      float b1v=b1[n];
      float wv=w2col[n];
      #pragma unroll
      for (int mt=0;mt<2;mt++){
        f32x4 acc=aH[mt];
        #pragma unroll
        for (int rr=0;rr<4;rr++){
          float hv=acc[rr]+b1v;
          if (signs){
            unsigned long long m0=__ballot(hv>0.f);
            if (c16==0) signs[(base+mt*16+g*4+rr)*16+nt]=(unsigned short)(m0>>(16*g));
          }
          pacc[mt][rr]=fmaf(fmaxf(hv,0.f),wv,pacc[mt][rr]);
        }
      }
    }
    #pragma unroll
    for (int mt=0;mt<2;mt++)
      #pragma unroll
      for (int rr=0;rr<4;rr++){
        float v=pacc[mt][rr];
        v+=__shfl_xor(v,1); v+=__shfl_xor(v,2); v+=__shfl_xor(v,4); v+=__shfl_xor(v,8);
        pacc[mt][rr]=v;
      }
    if (c16==0){
      float bb2=b2[0];
      #pragma unroll
      for (int mt=0;mt<2;mt++)
        #pragma unroll
        for (int rr=0;rr<4;rr++)
          out_sdf[base + mt*16 + g*4 + rr] = pacc[mt][rr] + bb2;
    }
  }
}

// --------- SDF backward: persistent full-B-LDS f16 MFMA ---------
__global__ __launch_bounds__(1024,4) void sdf_bwd_persist(
    const float* __restrict__ o, const float* __restrict__ dv, const float* __restrict__ z,
    int tilesTotal,
    const float* __restrict__ W0, const float* __restrict__ b0,
    const unsigned short* __restrict__ signs,
    const short* __restrict__ Th, const float* __restrict__ w2col,
    float* __restrict__ out_grad)
{
  __shared__ short ldsB[65536];
  __shared__ float w0s[3*HH];
  __shared__ float b0s[HH];
  __shared__ _Float16 w2h_s[HH];
  int t=threadIdx.x, wid=t>>6, lane=t&63, g=lane>>4, c16=lane&15;
  for (int i=t;i<3*HH;i+=1024) w0s[i]=W0[i];
  if (t<HH){ b0s[t]=b0[t]; w2h_s[t]=(_Float16)w2col[t]; }
  {
    const char* gb=(const char*)Th;
    #pragma unroll
    for (int c=0;c<8;c++){
      int ch=wid*8+c;
      gload_lds16(gb+ch*1024+lane*16,(void*)&ldsB[ch*512]);
    }
  }
  __syncthreads();
  ZInit zn{0,nullptr,nullptr,0.f,0.f,0.f,0.f};
  for (int tile=blockIdx.x*16+wid; tile<tilesTotal; tile+=gridDim.x*16){
    int base=tile*32;
    // lanes hold x of point base+(lane&31); fetch needed points via shfl
    float hx,hy,hz;
    {
      float pt[3];
      load_point2(o,dv,z,base+(lane&31),128,1,ZS,zn,pt,nullptr);
      hx=pt[0]; hy=pt[1]; hz=pt[2];
    }
    float xq[2][4][3];
    #pragma unroll
    for (int mt=0;mt<2;mt++)
      #pragma unroll
      for (int rr=0;rr<4;rr++){
        int p=mt*16+g*4+rr;
        xq[mt][rr][0]=__shfl(hx,p);
        xq[mt][rr][1]=__shfl(hy,p);
        xq[mt][rr][2]=__shfl(hz,p);
      }
    half8v af[2][8];
    #pragma unroll
    for (int mt=0;mt<2;mt++){
      int ptA = base + mt*16 + c16;
      #pragma unroll
      for (int s8=0;s8<8;s8++){
        int j0 = s8*32 + g*8;
        unsigned short wch = signs[ptA*16 + (j0>>4)];
        unsigned bits = ((unsigned)wch >> ((g&1)*8)) & 0xFFu;
        union { _Float16 h[8]; half8v v; } uh;
        #pragma unroll
        for (int jj=0;jj<8;jj++){
          bool on=(bits>>jj)&1u;
          uh.h[jj]= on ? w2h_s[j0+jj] : (_Float16)0.f;
        }
        af[mt][s8]=uh.v;
      }
    }
    float acc3[2][4][3];
    #pragma unroll
    for (int mt=0;mt<2;mt++)
      #pragma unroll
      for (int rr=0;rr<4;rr++){ acc3[mt][rr][0]=0.f; acc3[mt][rr][1]=0.f; acc3[mt][rr][2]=0.f; }
    for (int nt=0;nt<16;nt++){
      const short* Lb=&ldsB[nt*4096];
      f32x4 aH[2];
      aH[0]=(f32x4){0.f,0.f,0.f,0.f}; aH[1]=(f32x4){0.f,0.f,0.f,0.f};
      #pragma unroll
      for (int s8=0;s8<8;s8++){
        half8v bh = *(const half8v*)(Lb + s8*512 + lane*8);
        aH[0]=__builtin_amdgcn_mfma_f32_16x16x32_f16(af[0][s8],bh,aH[0],0,0,0);
        aH[1]=__builtin_amdgcn_mfma_f32_16x16x32_f16(af[1][s8],bh,aH[1],0,0,0);
      }
      int tn=nt*16+c16;
      float w0a=w0s[tn], w0b=w0s[HH+tn], w0c=w0s[2*HH+tn], bb=b0s[tn];
      #pragma unroll
      for (int mt=0;mt<2;mt++){
        f32x4 acc=aH[mt];
        #pragma unroll
        for (int rr=0;rr<4;rr++){
          float h0=fmaf(xq[mt][rr][0],w0a, fmaf(xq[mt][rr][1],w0b, fmaf(xq[mt][rr][2],w0c, bb)));
          float dh0=(h0>0.f)? acc[rr] : 0.f;
          acc3[mt][rr][0]=fmaf(dh0,w0a,acc3[mt][rr][0]);
          acc3[mt][rr][1]=fmaf(dh0,w0b,acc3[mt][rr][1]);
          acc3[mt][rr][2]=fmaf(dh0,w0c,acc3[mt][rr][2]);
        }
      }
    }
    #pragma unroll
    for (int mt=0;mt<2;mt++)
      #pragma unroll
      for (int rr=0;rr<4;rr++)
        #pragma unroll
        for (int cc=0;cc<3;cc++){
          float v=acc3[mt][rr][cc];
          v+=__shfl_xor(v,1); v+=__shfl_xor(v,2); v+=__shfl_xor(v,4); v+=__shfl_xor(v,8);
          acc3[mt][rr][cc]=v;
        }
    if (c16==0){
      #pragma unroll
      for (int mt=0;mt<2;mt++)
        #pragma unroll
        for (int rr=0;rr<4;rr++){
          int pt_ = base + mt*16 + g*4 + rr;
          out_grad[pt_*3+0]=acc3[mt][rr][0];
          out_grad[pt_*3+1]=acc3[mt][rr][1];
          out_grad[pt_*3+2]=acc3[mt][rr][2];
        }
    }
  }
}

// --------- batched NeRF MLP: persistent full-B-LDS f16 MFMA ---------
__global__ __launch_bounds__(1024,4) void nerf_mfma_persist(
    const float* __restrict__ rO, const float* __restrict__ rD,
    const float* __restrict__ rLo, const float* __restrict__ rHi,
    const float* __restrict__ zbuf, int ptsA, int SA, int SB, int NRA, int useZ, int midflag,
    int tilesTotal,
    const float* __restrict__ W0, const float* __restrict__ b0,
    const short* __restrict__ Bh, const float* __restrict__ b1,
    const float* __restrict__ W2, const float* __restrict__ b2,
    float* __restrict__ out_sigma, float* __restrict__ out_rgb)
{
  __shared__ short ldsB[65536];
  __shared__ float w0s[6*HH];
  __shared__ float b0s[HH];
  int t=threadIdx.x, wid=t>>6, lane=t&63, g=lane>>4, c16=lane&15;
  for (int i=t;i<6*HH;i+=1024) w0s[i]=W0[i];
  if (t<HH) b0s[t]=b0[t];
  {
    const char* gb=(const char*)Bh;
    #pragma unroll
    for (int c=0;c<8;c++){
      int ch=wid*8+c;
      gload_lds16(gb+ch*1024+lane*16,(void*)&ldsB[ch*512]);
    }
  }
  __syncthreads();
  for (int tile=blockIdx.x*16+wid; tile<tilesTotal; tile+=gridDim.x*16){
    int base=tile*32;
    float xv[2][6];
    #pragma unroll
    for (int mt=0;mt<2;mt++){
      int idx=base+mt*16+c16;
      int r,i,S;
      if (idx<ptsA){ S=SA; r=idx/SA; i=idx-r*SA; }
      else { int q=idx-ptsA; S=SB; r=NRA+q/SB; i=q-(q/SB)*SB; }
      float zz;
      if (!useZ){
        float a=rLo[r], b=rHi[r];
        zz = a + (b-a)*((float)i/(float)(S-1));
        if (midflag){
          float z1 = a + (b-a)*((float)(i+1)/(float)(S-1));
          zz = (i<S-1)? 0.5f*(zz+z1) : (zz+0.5f*SAMPLE_DIST);
        }
      } else {
        const float* zr = zbuf + r*128;
        zz = zr[i];
        if (midflag) zz = (i<S-1)? 0.5f*(zz+zr[i+1]) : (zz+0.5f*SAMPLE_DIST);
      }
      #pragma unroll
      for (int c=0;c<3;c++){
        float dc=rD[r*3+c];
        xv[mt][c]   = rO[r*3+c] + dc*zz;
        xv[mt][3+c] = dc;
      }
    }
    half8v af[2][8];
    #pragma unroll
    for (int mt=0;mt<2;mt++){
      float x0=xv[mt][0],x1=xv[mt][1],x2=xv[mt][2],x3=xv[mt][3],x4=xv[mt][4],x5=xv[mt][5];
      #pragma unroll
      for (int s8=0;s8<8;s8++){
        int nb = s8*32 + g*8;
        union { _Float16 h[8]; half8v v; } uh;
        #pragma unroll
        for (int j=0;j<8;j++){
          int n=nb+j;
          float a=b0s[n];
          a=fmaf(x0,w0s[n],a);
          a=fmaf(x1,w0s[HH+n],a);
          a=fmaf(x2,w0s[2*HH+n],a);
          a=fmaf(x3,w0s[3*HH+n],a);
          a=fmaf(x4,w0s[4*HH+n],a);
          a=fmaf(x5,w0s[5*HH+n],a);
          uh.h[j]=(_Float16)fmaxf(a,0.f);
        }
        af[mt][s8]=uh.v;
      }
    }
    float pacc[2][4][4];
    #pragma unroll
    for (int mt=0;mt<2;mt++)
      #pragma unroll
      for (int rr=0;rr<4;rr++){ pacc[mt][rr][0]=0.f; pacc[mt][rr][1]=0.f; pacc[mt][rr][2]=0.f; pacc[mt][rr][3]=0.f; }
    for (int nt=0;nt<16;nt++){
      const short* Lb=&ldsB[nt*4096];
      f32x4 aH[2];
      aH[0]=(f32x4){0.f,0.f,0.f,0.f}; aH[1]=(f32x4){0.f,0.f,0.f,0.f};
      #pragma unroll
      for (int s8=0;s8<8;s8++){
        half8v bh = *(const half8v*)(Lb + s8*512 + lane*8);
        aH[0]=__builtin_amdgcn_mfma_f32_16x16x32_f16(af[0][s8],bh,aH[0],0,0,0);
        aH[1]=__builtin_amdgcn_mfma_f32_16x16x32_f16(af[1][s8],bh,aH[1],0,0,0);
      }
      int n=nt*16+c16;
      float b1v=b1[n];
      float4 w2v = *(const float4*)(W2 + n*4);
      #pragma unroll
      for (int mt=0;mt<2;mt++){
        f32x4 acc=aH[mt];
        #pragma unroll
        for (int rr=0;rr<4;rr++){
          float hh=fmaxf(acc[rr]+b1v,0.f);
          pacc[mt][rr][0]=fmaf(hh,w2v.x,pacc[mt][rr][0]);
          pacc[mt][rr][1]=fmaf(hh,w2v.y,pacc[mt][rr][1]);
          pacc[mt][rr][2]=fmaf(hh,w2v.z,pacc[mt][rr][2]);
          pacc[mt][rr][3]=fmaf(hh,w2v.w,pacc[mt][rr][3]);
        }
      }
    }
    #pragma unroll
    for (int mt=0;mt<2;mt++)
      #pragma unroll
      for (int rr=0;rr<4;rr++)
        #pragma unroll
        for (int c=0;c<4;c++){
          float v=pacc[mt][rr][c];
          v+=__shfl_xor(v,1); v+=__shfl_xor(v,2); v+=__shfl_xor(v,4); v+=__shfl_xor(v,8);
          pacc[mt][rr][c]=v;
        }
    if (c16==0){
      float bb0=b2[0], bb1=b2[1], bb2v=b2[2], bb3=b2[3];
      #pragma unroll
      for (int mt=0;mt<2;mt++)
        #pragma unroll
        for (int rr=0;rr<4;rr++){
          int pt_ = base + mt*16 + g*4 + rr;
          out_sigma[pt_] = pacc[mt][rr][0] + bb0;
          out_rgb[pt_*3+0] = sigm(pacc[mt][rr][1] + bb1);
          out_rgb[pt_*3+1] = sigm(pacc[mt][rr][2] + bb2v);
          out_rgb[pt_*3+2] = sigm(pacc[mt][rr][3] + bb3);
        }
    }
  }
}

// --------- mask MLPs: two nets 3->256->1, sigmoid ---------
__global__ __launch_bounds__(256) void mask_kernel(
    const float* __restrict__ o, const float* __restrict__ dv, const float* __restrict__ z, int S,
    const float* __restrict__ Wa0, const float* __restrict__ ba0, const float* __restrict__ Wa1, const float* __restrict__ ba1,
    const float* __restrict__ Wb0, const float* __restrict__ bb0, const float* __restrict__ Wb1, const float* __restrict__ bb1,
    float* __restrict__ outA, float* __restrict__ outB)
{
  __shared__ __align__(16) float hA[PP][HH];
  __shared__ float pin[PP][4];
  __shared__ float part[PP][16];
  int t=threadIdx.x;
  int base=blockIdx.x*PP;
  if (t<PP){
    float pt[3];
    load_point(o,dv,z,base+t,S,1,pt,nullptr);
    pin[t][0]=pt[0]; pin[t][1]=pt[1]; pin[t][2]=pt[2];
  }
  __syncthreads();
  {
    float w0=Wa0[t], w1=Wa0[HH+t], w2=Wa0[2*HH+t], bb=ba0[t];
    #pragma unroll
    for (int p=0;p<PP;p++){
      float v = fmaf(pin[p][0],w0, fmaf(pin[p][1],w1, fmaf(pin[p][2],w2, bb)));
      hA[p][t]=fmaxf(v,0.f);
    }
  }
  __syncthreads();
  {
    int p=t>>4, g=t&15;
    float s=0.f;
    #pragma unroll
    for (int m=0;m<16;m++){ int j=g+16*m; s=fmaf(hA[p][j], Wa1[j], s); }
    part[p][g]=s;
  }
  __syncthreads();
  if (t<PP){
    float s=ba1[0];
    #pragma unroll
    for (int g=0;g<16;g++) s+=part[t][g];
    outA[base+t]=sigm(s);
  }
  __syncthreads();
  {
    float w0=Wb0[t], w1=Wb0[HH+t], w2=Wb0[2*HH+t], bb=bb0[t];
    #pragma unroll
    for (int p=0;p<PP;p++){
      float v = fmaf(pin[p][0],w0, fmaf(pin[p][1],w1, fmaf(pin[p][2],w2, bb)));
      hA[p][t]=fmaxf(v,0.f);
    }
  }
  __syncthreads();
  {
    int p=t>>4, g=t&15;
    float s=0.f;
    #pragma unroll
    for (int m=0;m<16;m++){ int j=g+16*m; s=fmaf(hA[p][j], Wb1[j], s); }
    part[p][g]=s;
  }
  __syncthreads();
  if (t<PP){
    float s=bb1[0];
    #pragma unroll
    for (int g=0;g<16;g++) s+=part[t][g];
    outB[base+t]=sigm(s);
  }
}

// --------- SDF up_sample + merge, one wave per ray ---------
__global__ __launch_bounds__(256) void upsample_wave_kernel(float* __restrict__ z,
    const float* __restrict__ sdf, const float* __restrict__ o, const float* __restrict__ dv,
    int S, float s, ZInit zi)
{
  __shared__ float zsh[4][128], ssh[4][128], csh[4][128], nzsh[4][16];
  int wave=threadIdx.x>>6, lane=threadIdx.x&63;
  int r=blockIdx.x*4+wave;
  float* zs=zsh[wave]; float* ss=ssh[wave]; float* cs=csh[wave]; float* nzs=nzsh[wave];
  for (int i=lane;i<S;i+=64){
    float zv;
    if (zi.on){
      float a=zi.loA[r], b=zi.hiA[r];
      zv = a + (b-a)*((float)i/(float)(S-1));
    } else zv = z[r*ZS+i];
    zs[i]=zv; ss[i]=sdf[r*S+i];
  }
  __syncthreads();
  float ox=o[r*3],oy=o[r*3+1],oz=o[r*3+2];
  float dx=dv[r*3],dy=dv[r*3+1],dz=dv[r*3+2];
  int M=S-1;
  auto alpha_at=[&](int k)->float{
    float z0=zs[k], z1=zs[k+1], s0=ss[k], s1=ss[k+1];
    float craw=(s1-s0)/(z1-z0+1e-5f);
    float cprev=(k>0)? (ss[k]-ss[k-1])/(zs[k]-zs[k-1]+1e-5f) : 0.f;
    float cv=fminf(craw,cprev);
    cv=fminf(fmaxf(cv,-1000.f),0.f);
    float px=ox+dx*z0, py=oy+dy*z0, pz=oz+dz*z0;
    float qx=ox+dx*z1, qy=oy+dy*z1, qz=oz+dz*z1;
    float r0=sqrtf(px*px+py*py+pz*pz);
    float r1=sqrtf(qx*qx+qy*qy+qz*qz);
    float inside=(r0<1.f||r1<1.f)?1.f:0.f;
    cv*=inside;
    float mid=0.5f*(s0+s1), dist=z1-z0;
    float pc=sigm((mid-0.5f*cv*dist)*s);
    float nc=sigm((mid+0.5f*cv*dist)*s);
    return (pc-nc+1e-5f)/(pc+1e-5f);
  };
  float al0=(lane<M)? alpha_at(lane):0.f;
  float al1=(lane+64<M)? alpha_at(lane+64):0.f;
  float f0=(lane<M)?(1.f-al0+1e-7f):1.f;
  float f1=(lane+64<M)?(1.f-al1+1e-7f):1.f;
  float ip0=iscan_prod(f0,lane);
  float tt=__shfl_up(ip0,1); float T0=(lane==0)?1.f:tt;
  float tot0=__shfl(ip0,63);
  float ip1=iscan_prod(f1,lane);
  float tu=__shfl_up(ip1,1); float T1=((lane==0)?1.f:tu)*tot0;
  float w0=(lane<M)? al0*T0+1e-5f:0.f;
  float w1=(lane+64<M)? al1*T1+1e-5f:0.f;
  float wsum=wave_sum(w0+w1);
  float inv=1.f/wsum;
  float is0=iscan_sum(w0,lane);
  float st0=__shfl(is0,63);
  float is1=iscan_sum(w1,lane)+st0;
  if (lane<M) cs[lane+1]=is0*inv;
  if (lane+64<M) cs[lane+64+1]=is1*inv;
  if (lane==0) cs[0]=0.f;
  __syncthreads();
  if (lane<16){
    float u=(lane+0.5f)/16.f;
    int lo=0,hi=S;
    while(lo<hi){ int m=(lo+hi)>>1; if(cs[m]<=u) lo=m+1; else hi=m; }
    int below=lo-1; below=below<0?0:(below>S-1?S-1:below);
    int above=lo>S-1?S-1:lo;
    float cb=cs[below], ca=cs[above], bb=zs[below], ba=zs[above];
    float dd=ca-cb; float den=(dd<1e-5f)?1.f:dd;
    nzs[lane]=bb+(u-cb)/den*(ba-bb);
  }
  __syncthreads();
  for (int i=lane;i<S;i+=64){
    float zi_=zs[i]; int cnt=0;
    #pragma unroll
    for (int j=0;j<16;j++) cnt += (nzs[j]<zi_)?1:0;
    z[r*ZS+i+cnt]=zi_;
  }
  if (lane<16){
    float v=nzs[lane]; int rk=0;
    #pragma unroll
    for (int j=0;j<16;j++) rk += ((nzs[j]<v)||(nzs[j]==v&&j<lane))?1:0;
    int lo=0,hi=S;
    while(lo<hi){ int m=(lo+hi)>>1; if(zs[m]<=v) lo=m+1; else hi=m; }
    z[r*ZS+lo+rk]=v;
  }
}

// --------- batched NeRF importance + merge, one wave per ray (4096 rays) ---------
__global__ __launch_bounds__(256) void nerf_imp_batch(float* __restrict__ zbuf,
    const float* __restrict__ sigma, const float* __restrict__ rLo, const float* __restrict__ rHi,
    int ptsA, int NRA)
{
  __shared__ float zsh[4][64], csh[4][64], nzsh[4][64];
  int wave=threadIdx.x>>6, lane=threadIdx.x&63;
  int r=blockIdx.x*4+wave;
  int S = (r<NRA)? 64 : 32;
  int n = S;
  int off = (r<NRA)? r*64 : ptsA + (r-NRA)*32;
  float* zs=zsh[wave]; float* cs=csh[wave]; float* nzs=nzsh[wave];
  if (lane<S){
    float a=rLo[r], b=rHi[r];
    zs[lane]= a + (b-a)*((float)lane/(float)(S-1));
  }
  __syncthreads();
  int M=S-1;
  float al=0.f;
  if (lane<M){
    float d_=zs[lane+1]-zs[lane];
    float sv=sigma[off+lane];
    al=1.f-__expf(-fmaxf(sv,0.f)*d_);
  }
  float f=(lane<M)?(1.f-al+1e-7f):1.f;
  float ip=iscan_prod(f,lane);
  float tt=__shfl_up(ip,1); float T=(lane==0)?1.f:tt;
  float w=(lane<M)? al*T+1e-5f:0.f;
  float wsum=wave_sum(w);
  float inv=1.f/wsum;
  float is=iscan_sum(w,lane);
  if (lane<M) cs[lane+1]=is*inv;
  if (lane==0) cs[0]=0.f;
  __syncthreads();
  if (lane<n){
    float u=(lane+0.5f)/(float)n;
    int lo=0,hi=S;
    while(lo<hi){ int m=(lo+hi)>>1; if(cs[m]<=u) lo=m+1; else hi=m; }
    int below=lo-1; below=below<0?0:(below>S-1?S-1:below);
    int above=lo>S-1?S-1:lo;
    float cb=cs[below], ca=cs[above], bb=zs[below], ba=zs[above];
    float dd=ca-cb; float den=(dd<1e-5f)?1.f:dd;
    nzs[lane]=bb+(u-cb)/den*(ba-bb);
  }
  __syncthreads();
  if (lane<S){
    float zi_=zs[lane]; int cnt=0;
    for (int j=0;j<n;j++) cnt += (nzs[j]<zi_)?1:0;
    zbuf[r*128+lane+cnt]=zi_;
  }
  if (lane<n){
    float v=nzs[lane]; int rk=0;
    for (int j=0;j<n;j++) rk += ((nzs[j]<v)||(nzs[j]==v&&j<lane))?1:0;
    int lo=0,hi=S;
    while(lo<hi){ int m=(lo+hi)>>1; if(zs[m]<=v) lo=m+1; else hi=m; }
    zbuf[r*128+lo+rk]=v;
  }
}

// --------- batched NeRF render, one wave per ray (4096 rays) ---------
__global__ __launch_bounds__(256) void nerf_render_batch(const float* __restrict__ zbuf,
    const float* __restrict__ sigma, const float* __restrict__ rgbp,
    int pts2A, int NRA,
    const float* __restrict__ mva, const float* __restrict__ mvb,
    float* __restrict__ c1b, float* __restrict__ m1b, float* __restrict__ m2b,
    float* __restrict__ cfb, float* __restrict__ czb, float* __restrict__ cbb)
{
  int wave=threadIdx.x>>6, lane=threadIdx.x&63;
  int r=blockIdx.x*4+wave;
  int S = (r<NRA)? 128 : 64;
  int off = (r<NRA)? r*128 : pts2A + (r-NRA)*64;
  const float* zr = zbuf + r*128;
  int domask = (r<1024);
  float a0=0.f,a1=0.f;
  if (lane<S){
    float d_=(lane<S-1)? zr[lane+1]-zr[lane] : SAMPLE_DIST;
    a0=1.f-__expf(-fmaxf(sigma[off+lane],0.f)*d_);
  }
  if (lane+64<S){
    int k=lane+64;
    float d_=(k<S-1)? zr[k+1]-zr[k] : SAMPLE_DIST;
    a1=1.f-__expf(-fmaxf(sigma[off+k],0.f)*d_);
  }
  float f0=(lane<S)?(1.f-a0+1e-7f):1.f;
  float f1=(lane+64<S)?(1.f-a1+1e-7f):1.f;
  float ip0=iscan_prod(f0,lane);
  float tt=__shfl_up(ip0,1); float T0=(lane==0)?1.f:tt;
  float tot0=__shfl(ip0,63);
  float ip1=iscan_prod(f1,lane);
  float tu=__shfl_up(ip1,1); float T1=((lane==0)?1.f:tu)*tot0;
  float w0=(lane<S)? a0*T0:0.f;
  float w1=(lane+64<S)? a1*T1:0.f;
  float c0=0,c1=0,c2=0,m1=0,m2=0;
  if (lane<S){
    int i0=off+lane;
    c0=w0*rgbp[i0*3]; c1=w0*rgbp[i0*3+1]; c2=w0*rgbp[i0*3+2];
    if (domask){ m1=w0*mva[i0]; m2=w0*mvb[i0]; }
  }
  if (lane+64<S){
    int i1=off+lane+64;
    c0=fmaf(w1,rgbp[i1*3],c0); c1=fmaf(w1,rgbp[i1*3+1],c1); c2=fmaf(w1,rgbp[i1*3+2],c2);
    if (domask){ m1=fmaf(w1,mva[i1],m1); m2=fmaf(w1,mvb[i1],m2); }
  }
  c0=wave_sum(c0); c1=wave_sum(c1); c2=wave_sum(c2);
  m1=wave_sum(m1); m2=wave_sum(m2);
  if (lane==0){
    int grp=r>>10, q=r&1023;
    float* outc = (grp==0)? c1b : (grp==1)? cfb : (grp==2)? czb : cbb;
    outc[q*3]=c0; outc[q*3+1]=c1; outc[q*3+2]=c2;
    if (grp==0){ m1b[q]=m1; m2b[q]=m2; }
  }
}

// --------- SDF render + hit/reflect/refract, one wave per ray (S=128) ---------
__global__ __launch_bounds__(256) void sdf_render_hit(const float* __restrict__ z,
    const float* __restrict__ sdf, const float* __restrict__ grad,
    const float* __restrict__ o, const float* __restrict__ dv,
    const float* __restrict__ svar,
    float* __restrict__ hitb, float* __restrict__ reflb, float* __restrict__ refrb)
{
  int wave=threadIdx.x>>6, lane=threadIdx.x&63;
  int r=blockIdx.x*4+wave;
  float inv_s=fminf(fmaxf(__expf(10.f*svar[0]),1e-6f),1e6f);
  float dx=dv[r*3],dy=dv[r*3+1],dz=dv[r*3+2];
  const float* zr=z+r*ZS;
  auto comp=[&](int k, float& alpha, float& midz, float& gx, float& gy, float& gz){
    float d_=(k<127)? zr[k+1]-zr[k] : SAMPLE_DIST;
    midz=zr[k]+0.5f*d_;
    int gi=(r*128+k)*3;
    gx=grad[gi]; gy=grad[gi+1]; gz=grad[gi+2];
    float tc=dx*gx+dy*gy+dz*gz;
    float ic=fminf(tc,0.f);
    float s_=sdf[r*128+k];
    float pc=sigm((s_-0.5f*ic*d_)*inv_s);
    float nc=sigm((s_+0.5f*ic*d_)*inv_s);
    alpha=fminf(fmaxf((pc-nc+1e-5f)/(pc+1e-5f),0.f),1.f);
  };
  float al0,mz0,g0x,g0y,g0z; comp(lane,al0,mz0,g0x,g0y,g0z);
  float al1,mz1,g1x,g1y,g1z; comp(lane+64,al1,mz1,g1x,g1y,g1z);
  float f0=1.f-al0+1e-7f, f1=1.f-al1+1e-7f;
  float ip0=iscan_prod(f0,lane);
  float tt=__shfl_up(ip0,1); float T0=(lane==0)?1.f:tt;
  float tot0=__shfl(ip0,63);
  float ip1=iscan_prod(f1,lane);
  float tu=__shfl_up(ip1,1); float T1=((lane==0)?1.f:tu)*tot0;
  float w0=al0*T0, w1=al1*T1;
  float n0=1.f/(sqrtf(g0x*g0x+g0y*g0y+g0z*g0z)+1e-12f);
  float n1=1.f/(sqrtf(g1x*g1x+g1y*g1y+g1z*g1z)+1e-12f);
  float dep=w0*mz0+w1*mz1;
  float sx=w0*n0*g0x+w1*n1*g1x;
  float sy=w0*n0*g0y+w1*n1*g1y;
  float sz=w0*n0*g0z+w1*n1*g1z;
  dep=wave_sum(dep); sx=wave_sum(sx); sy=wave_sum(sy); sz=wave_sum(sz);
  if (lane==0){
    float nn=1.f/(sqrtf(sx*sx+sy*sy+sz*sz)+1e-12f);
    float nx=sx*nn, ny=sy*nn, nz=sz*nn;
    hitb[r*3]  = o[r*3]  +dx*dep;
    hitb[r*3+1]= o[r*3+1]+dy*dep;
    hitb[r*3+2]= o[r*3+2]+dz*dep;
    float cs=dx*nx+dy*ny+dz*nz;
    if (cs>0.f){ nx=-nx; ny=-ny; nz=-nz; }
    float cosi=-(dx*nx+dy*ny+dz*nz);
    float rx=dx+2.f*cosi*nx, ry=dy+2.f*cosi*ny, rz=dz+2.f*cosi*nz;
    float eta=1.f/1.5f;
    float k=1.f-eta*eta*(1.f-cosi*cosi);
    float sq=sqrtf(fmaxf(k,0.f));
    float tx=eta*dx+(eta*cosi-sq)*nx;
    float ty=eta*dy+(eta*cosi-sq)*ny;
    float tz=eta*dz+(eta*cosi-sq)*nz;
    if (k<0.f){ tx=rx; ty=ry; tz=rz; }
    float rn=1.f/(sqrtf(rx*rx+ry*ry+rz*rz)+1e-12f);
    reflb[r*3]=rx*rn; reflb[r*3+1]=ry*rn; reflb[r*3+2]=rz*rn;
    float tn=1.f/(sqrtf(tx*tx+ty*ty+tz*tz)+1e-12f);
    refrb[r*3]=tx*tn; refrb[r*3+1]=ty*tn; refrb[r*3+2]=tz*tn;
  }
}

// --------- final composition ---------
__global__ void compose_kernel(const float* __restrict__ c1b, const float* __restrict__ m1b,
    const float* __restrict__ m2b, const float* __restrict__ cfb, const float* __restrict__ czb,
    const float* __restrict__ cbb, float* __restrict__ out)
{
  int r = blockIdx.x*blockDim.x + threadIdx.x;
  if (r >= NB) return;
  float m1=m1b[r], m2=m2b[r];
  #pragma unroll
  for (int c=0;c<3;c++){
    float v = c1b[r*3+c]*(1.f-m2) + cfb[r*3+c]*m2;
    float rz = 0.5f*czb[r*3+c] + 0.5f*cbb[r*3+c];
    out[r*3+c] = v*(1.f-m1) + rz*m1;
  }
}

extern "C" void kernel_launch(void* const* d_in, const int* in_sizes, int n_in,
                              void* d_out, int out_size, void* d_ws, size_t ws_size,
                              hipStream_t stream)
{
  const float* rays_o=(const float*)d_in[0];
  const float* rays_d=(const float*)d_in[1];
  const float* nearA =(const float*)d_in[2];
  const float* farA  =(const float*)d_in[3];
  const float* Ws0=(const float*)d_in[4];
  const float* bs0=(const float*)d_in[5];
  const float* Ws1=(const float*)d_in[6];
  const float* bs1=(const float*)d_in[7];
  const float* Ws2=(const float*)d_in[8];
  const float* bs2=(const float*)d_in[9];
  const float* svar=(const float*)d_in[10];
  const float* Wn0=(const float*)d_in[15];
  const float* bn0=(const float*)d_in[16];
  const float* Wn1=(const float*)d_in[17];
  const float* bn1=(const float*)d_in[18];
  const float* Wn2=(const float*)d_in[19];
  const float* bn2=(const float*)d_in[20];
  const float* Wrf0=(const float*)d_in[21];
  const float* brf0=(const float*)d_in[22];
  const float* Wrf1=(const float*)d_in[23];
  const float* brf1=(const float*)d_in[24];
  const float* Wrl0=(const float*)d_in[25];
  const float* brl0=(const float*)d_in[26];
  const float* Wrl1=(const float*)d_in[27];
  const float* brl1=(const float*)d_in[28];

  const int NRA   = 2048;
  const int PTS1A = 2048*64;
  const int PTS2A = 2048*128;

  float* ws=(float*)d_ws;
  float* zbuf = ws;  ws += 4096*128;
  float* sdfb = ws;  ws += 393216;
  float* uni  = ws;  ws += 1441792;
  float* gradb = uni;
  unsigned short* signsb = (unsigned short*)(uni + 393216);
  float* rgbp = uni;
  float* mv1  = ws;  ws += PTS1A;
  float* mv2  = ws;  ws += PTS1A;
  float* W1T  = ws;  ws += HH*HH;
  float* w2c  = ws;  ws += HH;
  float* rO   = ws;  ws += 4096*3;
  float* rD   = ws;  ws += 4096*3;
  float* rLo  = ws;  ws += 4096;
  float* rHi  = ws;  ws += 4096;
  float* hitb = ws;  ws += NB*3;
  float* reflb= ws;  ws += NB*3;
  float* refrb= ws;  ws += NB*3;
  float* c1b  = ws;  ws += NB*3;
  float* m1b  = ws;  ws += NB;
  float* m2b  = ws;  ws += NB;
  float* cfb  = ws;  ws += NB*3;
  float* czb  = ws;  ws += NB*3;
  float* cbb  = ws;  ws += NB*3;
  short* bfragN = (short*)ws; ws += HH*HH/2;
  short* bfragS = (short*)ws; ws += HH*HH/2;
  short* bfragT = (short*)ws; ws += HH*HH/2;

  const int RB = (NB+255)/256;
  const int WB = NB/4;

  ZInit ziNone{0,nullptr,nullptr,0.f,0.f,0.f,0.f};
  ZInit ziNF  {1,nearA,farA,0.f,0.f,0.f,0.f};

  auto tgrid=[](int tiles){ int b=(tiles+15)/16; return b<256?b:256; };

  prep_kernel<<<256,256,0,stream>>>(Ws1, Ws2, W1T, w2c);
  prep_bfrag_kernel<<<256,256,0,stream>>>(Wn1, bfragN);
  prep_bfrag_kernel<<<256,256,0,stream>>>(Ws1, bfragS);
  prep_bfrag_kernel<<<256,256,0,stream>>>(W1T, bfragT);

  // ---- stage 1: importance_sdf (main rays, zbuf stride 128) ----
  for (int i=0;i<4;i++){
    int S=64+16*i;
    float sscale=64.f*(float)(1<<i);
    int tiles = NB*S/32;
    sdf_mfma_persist<<<tgrid(tiles),1024,0,stream>>>(rays_o,rays_d,zbuf,S,0,ZS,(i==0?ziNF:ziNone),tiles,
        Ws0,bs0, bfragS,bs1, w2c,bs2, sdfb, nullptr);
    upsample_wave_kernel<<<WB,256,0,stream>>>(zbuf,sdfb,rays_o,rays_d,S,sscale,(i==0?ziNF:ziNone));
  }

  // ---- stage 2: render_sdf -> hit/refl/refr ----
  {
    int tiles = NB*128/32;
    sdf_mfma_persist<<<tgrid(tiles),1024,0,stream>>>(rays_o,rays_d,zbuf,128,1,ZS,ziNone,tiles,
        Ws0,bs0, bfragS,bs1, w2c,bs2, sdfb, signsb);
    sdf_bwd_persist<<<tgrid(tiles),1024,0,stream>>>(rays_o,rays_d,zbuf, tiles,
        Ws0,bs0, signsb, bfragT, w2c, gradb);
  }
  sdf_render_hit<<<WB,256,0,stream>>>(zbuf,sdfb,gradb,rays_o,rays_d,svar, hitb,reflb,refrb);

  // ---- batched NeRF: build 4096-virtual-ray table ----
  build_rays_kernel<<<16,256,0,stream>>>(rays_o,rays_d,nearA,farA, hitb,reflb,refrb, rO,rD,rLo,rHi);

  // pass 1: eval at analytic z (S=64 for rays<2048, S=32 else) -> sigma
  {
    int tiles=(PTS1A + 2048*32)/32;
    nerf_mfma_persist<<<tgrid(tiles),1024,0,stream>>>(rO,rD,rLo,rHi, zbuf,
        PTS1A, 64, 32, NRA, 0, 0, tiles,
        Wn0,bn0, bfragN,bn1, Wn2,bn2, sdfb,rgbp);
  }
  // importance + merge -> zbuf (stride 128)
  nerf_imp_batch<<<4096/4,256,0,stream>>>(zbuf, sdfb, rLo,rHi, PTS1A, NRA);
  // pass 2: eval at midpoints of merged z (S=128 / 64) -> sigma+rgb
  {
    int tiles=(PTS2A + 2048*64)/32;
    nerf_mfma_persist<<<tgrid(tiles),1024,0,stream>>>(rO,rD,rLo,rHi, zbuf,
        PTS2A, 128, 64, NRA, 1, 1, tiles,
        Wn0,bn0, bfragN,bn1, Wn2,bn2, sdfb,rgbp);
  }
  // masks (main rays only)
  mask_kernel<<<NB*128/PP,256,0,stream>>>(rays_o,rays_d,zbuf,128, Wrf0,brf0,Wrf1,brf1, Wrl0,brl0,Wrl1,brl1, mv1,mv2);
  // render all 4096 rays
  nerf_render_batch<<<4096/4,256,0,stream>>>(zbuf, sdfb, rgbp, PTS2A, NRA, mv1,mv2,
      c1b,m1b,m2b, cfb,czb,cbb);

  // ---- compose ----
  compose_kernel<<<RB,256,0,stream>>>(c1b,m1b,m2b,cfb,czb,cbb,(float*)d_out);
}

// Round 13
// 391.093 us; speedup vs baseline: 6.1267x; 6.1267x over previous
//
#include <hip/hip_runtime.h>

#define NB 1024
#define HH 256
#define ZS 128
#define PP 16
#define SAMPLE_DIST 0.03125f

typedef __attribute__((ext_vector_type(8))) _Float16 half8v;
typedef __attribute__((ext_vector_type(4))) float f32x4;

struct ZInit { int on; const float* loA; const float* hiA; float lo0,hi0,lo1,hi1; };

__device__ __forceinline__ float sigm(float x){ return 1.0f/(1.0f+__expf(-x)); }

// async global->LDS, 16B per lane; lds dest wave-uniform base (+lane*16 by HW)
__device__ __forceinline__ void gload_lds16(const void* g, void* l){
  __builtin_amdgcn_global_load_lds(
      (const __attribute__((address_space(1))) unsigned int*)g,
      (__attribute__((address_space(3))) unsigned int*)l, 16, 0, 0);
}

__device__ __forceinline__ float iscan_prod(float v, int lane){
  #pragma unroll
  for (int o=1;o<64;o<<=1){ float u=__shfl_up(v,o); if(lane>=o) v*=u; }
  return v;
}
__device__ __forceinline__ float iscan_sum(float v, int lane){
  #pragma unroll
  for (int o=1;o<64;o<<=1){ float u=__shfl_up(v,o); if(lane>=o) v+=u; }
  return v;
}
__device__ __forceinline__ float wave_sum(float v){
  #pragma unroll
  for (int o=1;o<64;o<<=1) v += __shfl_xor(v,o);
  return v;
}

// point loader with optional analytic z-init (sdf kernels, main rays)
__device__ __forceinline__ void load_point2(const float* __restrict__ o, const float* __restrict__ dv,
    const float* __restrict__ z, int idx, int S, int midflag, int zst, ZInit zi, float* pt, float* dir)
{
  int r = idx / S;
  int i = idx - r*S;
  float zz;
  if (zi.on){
    float a=zi.loA[r], b=zi.hiA[r];
    zz = a + (b-a)*((float)i/(float)(S-1));
    if (midflag){
      float z1 = a + (b-a)*((float)(i+1)/(float)(S-1));
      zz = (i < S-1) ? 0.5f*(zz+z1) : (zz + 0.5f*SAMPLE_DIST);
    }
  } else {
    const float* zr = z + r*zst;
    zz = zr[i];
    if (midflag) zz = (i < S-1) ? 0.5f*(zz + zr[i+1]) : (zz + 0.5f*SAMPLE_DIST);
  }
  #pragma unroll
  for (int c=0;c<3;c++){
    float dc = dv[r*3+c];
    pt[c] = o[r*3+c] + dc*zz;
    if (dir) dir[c] = dc;
  }
}

// legacy loader (mask kernel)
__device__ __forceinline__ void load_point(const float* __restrict__ o, const float* __restrict__ dv,
    const float* __restrict__ z, int idx, int S, int midflag, float* pt, float* dir)
{
  int r = idx / S;
  int i = idx - r*S;
  const float* zr = z + r*ZS;
  float zz = zr[i];
  if (midflag) zz = (i < S-1) ? 0.5f*(zz + zr[i+1]) : (zz + 0.5f*SAMPLE_DIST);
  #pragma unroll
  for (int c=0;c<3;c++){
    float dc = dv[r*3+c];
    pt[c] = o[r*3+c] + dc*zz;
    if (dir) dir[c] = dc;
  }
}

// --------- prep: transpose W_sdf1, extract col0 of W_sdf2 ---------
__global__ __launch_bounds__(256) void prep_kernel(const float* __restrict__ W1, const float* __restrict__ W2,
    float* __restrict__ W1T, float* __restrict__ w2col)
{
  int idx = blockIdx.x*256 + threadIdx.x;
  int j = idx >> 8, k = idx & 255;
  W1T[j*HH + k] = W1[k*HH + j];
  if (idx < HH) w2col[idx] = W2[idx*257];
}

// --------- prep: pack 256x256 f32 weight into f16 MFMA B-fragment order ---------
__global__ __launch_bounds__(256) void prep_bfrag_kernel(const float* __restrict__ W1,
    short* __restrict__ Bh)
{
  int idx = blockIdx.x*256 + threadIdx.x;
  int j = idx & 7;
  int lane = (idx>>3) & 63;
  int s = (idx>>9) & 7;
  int nt = idx >> 12;
  int k = s*32 + ((lane>>4)<<3) + j;
  int n = nt*16 + (lane&15);
  union { _Float16 h; short s; } u;
  u.h = (_Float16)W1[k*256 + n];
  Bh[idx] = u.s;
}

// --------- ray table build: 4096 virtual rays ---------
__global__ void build_rays_kernel(const float* __restrict__ ro, const float* __restrict__ rd,
    const float* __restrict__ nearA, const float* __restrict__ farA,
    const float* __restrict__ hit, const float* __restrict__ refl, const float* __restrict__ refr,
    float* __restrict__ rO, float* __restrict__ rD, float* __restrict__ rLo, float* __restrict__ rHi)
{
  int r = blockIdx.x*256 + threadIdx.x;
  if (r >= 4096) return;
  int m = r>>10, q = r&1023;
  const float* so; const float* sd; float lo,hi;
  if (m==0){ so=ro+q*3; sd=rd+q*3; lo=nearA[q]; hi=farA[q]; }
  else if (m==1){ so=hit+q*3; sd=refl+q*3; lo=0.05f; hi=3.7f; }
  else if (m==2){ so=hit+q*3; sd=refr+q*3; lo=0.f; hi=3.7f; }
  else { so=hit+q*3; sd=refr+q*3; lo=0.5f; hi=3.7f; }
  rO[r*3]=so[0]; rO[r*3+1]=so[1]; rO[r*3+2]=so[2];
  rD[r*3]=sd[0]; rD[r*3+1]=sd[1]; rD[r*3+2]=sd[2];
  rLo[r]=lo; rHi[r]=hi;
}

// --------- SDF value MLP via f16 MFMA (nt-pair LDS double buffer, as round 10) ---------
__global__ __launch_bounds__(256) void sdf_mfma_kernel(
    const float* __restrict__ o, const float* __restrict__ dv, const float* __restrict__ z,
    int S, int midflag, int zst, ZInit zi,
    const float* __restrict__ W0, const float* __restrict__ b0,
    const short* __restrict__ Bh, const float* __restrict__ b1,
    const float* __restrict__ w2col, const float* __restrict__ b2,
    float* __restrict__ out_sdf, unsigned short* __restrict__ signs)
{
  __shared__ short ldsB[2][8192];
  __shared__ float xs[128][5];
  __shared__ float w0s[3*HH];
  __shared__ float b0s[HH];
  int t = threadIdx.x;
  int base = blockIdx.x*128;
  int wave=t>>6, lane=t&63, g=lane>>4, c16=lane&15;
  for (int i=t;i<3*HH;i+=256) w0s[i]=W0[i];
  b0s[t]=b0[t];
  if (t<128){
    float pt[3];
    load_point2(o,dv,z,base+t,S,midflag,zst,zi,pt,nullptr);
    xs[t][0]=pt[0]; xs[t][1]=pt[1]; xs[t][2]=pt[2];
  }
  {
    const char* gb = (const char*)Bh;
    #pragma unroll
    for (int c=0;c<4;c++){
      int ch = wave*4 + c;
      gload_lds16(gb + ch*1024 + lane*16, (void*)&ldsB[0][ch*512]);
    }
  }
  __syncthreads();
  half8v af[2][8];
  #pragma unroll
  for (int mt=0;mt<2;mt++){
    const float* xp = xs[wave*32 + mt*16 + c16];
    float x0=xp[0],x1=xp[1],x2=xp[2];
    #pragma unroll
    for (int s8=0;s8<8;s8++){
      int nb = s8*32 + g*8;
      union { _Float16 h[8]; half8v v; } uh;
      #pragma unroll
      for (int j=0;j<8;j++){
        int n=nb+j;
        float a=b0s[n];
        a=fmaf(x0,w0s[n],a);
        a=fmaf(x1,w0s[HH+n],a);
        a=fmaf(x2,w0s[2*HH+n],a);
        uh.h[j]=(_Float16)fmaxf(a,0.f);
      }
      af[mt][s8]=uh.v;
    }
  }
  float pacc[2][4];
  #pragma unroll
  for (int mt=0;mt<2;mt++){ pacc[mt][0]=0.f; pacc[mt][1]=0.f; pacc[mt][2]=0.f; pacc[mt][3]=0.f; }
  int buf=0;
  for (int ntp=0;ntp<8;ntp++){
    if (ntp<7){
      const char* gb = (const char*)(Bh + 2*(ntp+1)*4096);
      #pragma unroll
      for (int c=0;c<4;c++){
        int ch = wave*4 + c;
        gload_lds16(gb + ch*1024 + lane*16, (void*)&ldsB[buf^1][ch*512]);
      }
    }
    int nt0=2*ntp;
    f32x4 aH[2][2];
    #pragma unroll
    for (int mt=0;mt<2;mt++)
      #pragma unroll
      for (int h=0;h<2;h++) aH[mt][h]=(f32x4){0.f,0.f,0.f,0.f};
    const short* Lb = &ldsB[buf][0];
    #pragma unroll
    for (int s8=0;s8<8;s8++){
      half8v bh0 = *(const half8v*)(Lb + s8*512 + lane*8);
      half8v bh1 = *(const half8v*)(Lb + 4096 + s8*512 + lane*8);
      #pragma unroll
      for (int mt=0;mt<2;mt++){
        aH[mt][0] = __builtin_amdgcn_mfma_f32_16x16x32_f16(af[mt][s8], bh0, aH[mt][0], 0,0,0);
        aH[mt][1] = __builtin_amdgcn_mfma_f32_16x16x32_f16(af[mt][s8], bh1, aH[mt][1], 0,0,0);
      }
    }
    #pragma unroll
    for (int h=0;h<2;h++){
      int nt = nt0+h;
      int n = nt*16 + c16;
      float b1v = b1[n];
      float wv = w2col[n];
      #pragma unroll
      for (int mt=0;mt<2;mt++){
        f32x4 acc = aH[mt][h];
        #pragma unroll
        for (int rr=0;rr<4;rr++){
          float hv = acc[rr]+b1v;
          if (signs){
            unsigned long long m0 = __ballot(hv>0.f);
            if (c16==0) signs[(base+wave*32+mt*16+g*4+rr)*16+nt] = (unsigned short)(m0>>(16*g));
          }
          pacc[mt][rr]=fmaf(fmaxf(hv,0.f),wv,pacc[mt][rr]);
        }
      }
    }
    __syncthreads();
    buf^=1;
  }
  #pragma unroll
  for (int mt=0;mt<2;mt++)
    #pragma unroll
    for (int rr=0;rr<4;rr++){
      float v=pacc[mt][rr];
      v+=__shfl_xor(v,1); v+=__shfl_xor(v,2); v+=__shfl_xor(v,4); v+=__shfl_xor(v,8);
      pacc[mt][rr]=v;
    }
  if (c16==0){
    float bb2=b2[0];
    #pragma unroll
    for (int mt=0;mt<2;mt++)
      #pragma unroll
      for (int rr=0;rr<4;rr++)
        out_sdf[base + wave*32 + mt*16 + g*4 + rr] = pacc[mt][rr] + bb2;
  }
}

// --------- SDF backward via f16 MFMA (nt-pair LDS double buffer, as round 10) ---------
__global__ __launch_bounds__(256) void sdf_bwd_mfma_kernel(
    const float* __restrict__ o, const float* __restrict__ dv, const float* __restrict__ z,
    const float* __restrict__ W0, const float* __restrict__ b0,
    const unsigned short* __restrict__ signs,
    const short* __restrict__ Th,
    const float* __restrict__ w2col,
    float* __restrict__ out_grad)
{
  __shared__ short ldsB[2][8192];
  __shared__ float xs[128][5];
  __shared__ float w0s[3*HH];
  __shared__ float b0s[HH];
  __shared__ _Float16 w2h_s[HH];
  int t = threadIdx.x;
  int base = blockIdx.x*128;
  int wave=t>>6, lane=t&63, g=lane>>4, c16=lane&15;
  for (int i=t;i<3*HH;i+=256) w0s[i]=W0[i];
  b0s[t]=b0[t];
  w2h_s[t]=(_Float16)w2col[t];
  if (t<128){
    float pt[3];
    ZInit zn{0,nullptr,nullptr,0,0,0,0};
    load_point2(o,dv,z,base+t,128,1,ZS,zn,pt,nullptr);
    xs[t][0]=pt[0]; xs[t][1]=pt[1]; xs[t][2]=pt[2];
  }
  {
    const char* gb = (const char*)Th;
    #pragma unroll
    for (int c=0;c<4;c++){
      int ch = wave*4 + c;
      gload_lds16(gb + ch*1024 + lane*16, (void*)&ldsB[0][ch*512]);
    }
  }
  __syncthreads();
  half8v af[2][8];
  #pragma unroll
  for (int mt=0;mt<2;mt++){
    int ptA = base + wave*32 + mt*16 + c16;
    #pragma unroll
    for (int s8=0;s8<8;s8++){
      int j0 = s8*32 + g*8;
      unsigned short wch = signs[ptA*16 + (j0>>4)];
      unsigned bits = ((unsigned)wch >> ((g&1)*8)) & 0xFFu;
      union { _Float16 h[8]; half8v v; } uh;
      #pragma unroll
      for (int jj=0;jj<8;jj++){
        bool on = (bits>>jj)&1u;
        uh.h[jj] = on ? w2h_s[j0+jj] : (_Float16)0.f;
      }
      af[mt][s8]=uh.v;
    }
  }
  float acc3[2][4][3];
  #pragma unroll
  for (int mt=0;mt<2;mt++)
    #pragma unroll
    for (int rr=0;rr<4;rr++){ acc3[mt][rr][0]=0.f; acc3[mt][rr][1]=0.f; acc3[mt][rr][2]=0.f; }
  int buf=0;
  for (int ntp=0;ntp<8;ntp++){
    if (ntp<7){
      const char* gb = (const char*)(Th + 2*(ntp+1)*4096);
      #pragma unroll
      for (int c=0;c<4;c++){
        int ch = wave*4 + c;
        gload_lds16(gb + ch*1024 + lane*16, (void*)&ldsB[buf^1][ch*512]);
      }
    }
    int nt0=2*ntp;
    f32x4 aH[2][2];
    #pragma unroll
    for (int mt=0;mt<2;mt++)
      #pragma unroll
      for (int h=0;h<2;h++) aH[mt][h]=(f32x4){0.f,0.f,0.f,0.f};
    const short* Lb = &ldsB[buf][0];
    #pragma unroll
    for (int s8=0;s8<8;s8++){
      half8v bh0 = *(const half8v*)(Lb + s8*512 + lane*8);
      half8v bh1 = *(const half8v*)(Lb + 4096 + s8*512 + lane*8);
      #pragma unroll
      for (int mt=0;mt<2;mt++){
        aH[mt][0] = __builtin_amdgcn_mfma_f32_16x16x32_f16(af[mt][s8], bh0, aH[mt][0], 0,0,0);
        aH[mt][1] = __builtin_amdgcn_mfma_f32_16x16x32_f16(af[mt][s8], bh1, aH[mt][1], 0,0,0);
      }
    }
    #pragma unroll
    for (int h=0;h<2;h++){
      int nt = nt0+h;
      int tn = nt*16 + c16;
      float w0a=w0s[tn], w0b=w0s[HH+tn], w0c=w0s[2*HH+tn], bb=b0s[tn];
      #pragma unroll
      for (int mt=0;mt<2;mt++){
        f32x4 acc = aH[mt][h];
        #pragma unroll
        for (int rr=0;rr<4;rr++){
          const float* xq = xs[wave*32 + mt*16 + g*4 + rr];
          float h0 = fmaf(xq[0],w0a, fmaf(xq[1],w0b, fmaf(xq[2],w0c, bb)));
          float dh0 = (h0>0.f) ? acc[rr] : 0.f;
          acc3[mt][rr][0]=fmaf(dh0,w0a,acc3[mt][rr][0]);
          acc3[mt][rr][1]=fmaf(dh0,w0b,acc3[mt][rr][1]);
          acc3[mt][rr][2]=fmaf(dh0,w0c,acc3[mt][rr][2]);
        }
      }
    }
    __syncthreads();
    buf^=1;
  }
  #pragma unroll
  for (int mt=0;mt<2;mt++)
    #pragma unroll
    for (int rr=0;rr<4;rr++)
      #pragma unroll
      for (int cc=0;cc<3;cc++){
        float v=acc3[mt][rr][cc];
        v+=__shfl_xor(v,1); v+=__shfl_xor(v,2); v+=__shfl_xor(v,4); v+=__shfl_xor(v,8);
        acc3[mt][rr][cc]=v;
      }
  if (c16==0){
    #pragma unroll
    for (int mt=0;mt<2;mt++)
      #pragma unroll
      for (int rr=0;rr<4;rr++){
        int pt_ = base + wave*32 + mt*16 + g*4 + rr;
        out_grad[pt_*3+0]=acc3[mt][rr][0];
        out_grad[pt_*3+1]=acc3[mt][rr][1];
        out_grad[pt_*3+2]=acc3[mt][rr][2];
      }
  }
}

// --------- batched NeRF MLP via f16 MFMA (nt-pair dbuf; per-lane x, no xs LDS) ---------
__global__ __launch_bounds__(256) void nerf_mfma_batch(
    const float* __restrict__ rO, const float* __restrict__ rD,
    const float* __restrict__ rLo, const float* __restrict__ rHi,
    const float* __restrict__ zbuf, int ptsA, int lgSA, int lgSB, int NRA, int useZ, int midflag,
    const float* __restrict__ W0, const float* __restrict__ b0,
    const short* __restrict__ Bh, const float* __restrict__ b1,
    const float* __restrict__ W2, const float* __restrict__ b2,
    float* __restrict__ out_sigma, float* __restrict__ out_rgb)
{
  __shared__ short ldsB[2][8192];
  __shared__ float w0s[6*HH];
  __shared__ float b0s[HH];
  int t = threadIdx.x;
  int base = blockIdx.x*128;
  int wave=t>>6, lane=t&63, g=lane>>4, c16=lane&15;
  for (int i=t;i<6*HH;i+=256) w0s[i]=W0[i];
  b0s[t]=b0[t];
  {
    const char* gb = (const char*)Bh;
    #pragma unroll
    for (int c=0;c<4;c++){
      int ch = wave*4 + c;
      gload_lds16(gb + ch*1024 + lane*16, (void*)&ldsB[0][ch*512]);
    }
  }
  // per-lane point computation (registers; no xs LDS)
  float xv[2][6];
  #pragma unroll
  for (int mt=0;mt<2;mt++){
    int idx = base + wave*32 + mt*16 + c16;
    int r,i,S;
    if (idx<ptsA){ r=idx>>lgSA; i=idx-(r<<lgSA); S=1<<lgSA; }
    else { int q=idx-ptsA; int rq=q>>lgSB; r=NRA+rq; i=q-(rq<<lgSB); S=1<<lgSB; }
    float zz;
    if (!useZ){
      float a=rLo[r], b=rHi[r];
      zz = a + (b-a)*((float)i/(float)(S-1));
      if (midflag){
        float z1 = a + (b-a)*((float)(i+1)/(float)(S-1));
        zz = (i<S-1)? 0.5f*(zz+z1) : (zz+0.5f*SAMPLE_DIST);
      }
    } else {
      const float* zr = zbuf + r*128;
      zz = zr[i];
      if (midflag) zz = (i<S-1)? 0.5f*(zz+zr[i+1]) : (zz+0.5f*SAMPLE_DIST);
    }
    #pragma unroll
    for (int c=0;c<3;c++){
      float dc=rD[r*3+c];
      xv[mt][c]   = rO[r*3+c] + dc*zz;
      xv[mt][3+c] = dc;
    }
  }
  __syncthreads();
  half8v af[2][8];
  #pragma unroll
  for (int mt=0;mt<2;mt++){
    float x0=xv[mt][0],x1=xv[mt][1],x2=xv[mt][2],x3=xv[mt][3],x4=xv[mt][4],x5=xv[mt][5];
    #pragma unroll
    for (int s8=0;s8<8;s8++){
      int nb = s8*32 + g*8;
      union { _Float16 h[8]; half8v v; } uh;
      #pragma unroll
      for (int j=0;j<8;j++){
        int n=nb+j;
        float a=b0s[n];
        a=fmaf(x0,w0s[n],a);
        a=fmaf(x1,w0s[HH+n],a);
        a=fmaf(x2,w0s[2*HH+n],a);
        a=fmaf(x3,w0s[3*HH+n],a);
        a=fmaf(x4,w0s[4*HH+n],a);
        a=fmaf(x5,w0s[5*HH+n],a);
        uh.h[j]=(_Float16)fmaxf(a,0.f);
      }
      af[mt][s8]=uh.v;
    }
  }
  float pacc[2][4][4];
  #pragma unroll
  for (int mt=0;mt<2;mt++)
    #pragma unroll
    for (int rr=0;rr<4;rr++){ pacc[mt][rr][0]=0.f; pacc[mt][rr][1]=0.f; pacc[mt][rr][2]=0.f; pacc[mt][rr][3]=0.f; }
  int buf=0;
  for (int ntp=0;ntp<8;ntp++){
    if (ntp<7){
      const char* gb = (const char*)(Bh + 2*(ntp+1)*4096);
      #pragma unroll
      for (int c=0;c<4;c++){
        int ch = wave*4 + c;
        gload_lds16(gb + ch*1024 + lane*16, (void*)&ldsB[buf^1][ch*512]);
      }
    }
    int nt0=2*ntp;
    f32x4 aH[2][2];
    #pragma unroll
    for (int mt=0;mt<2;mt++)
      #pragma unroll
      for (int h=0;h<2;h++) aH[mt][h]=(f32x4){0.f,0.f,0.f,0.f};
    const short* Lb = &ldsB[buf][0];
    #pragma unroll
    for (int s8=0;s8<8;s8++){
      half8v bh0 = *(const half8v*)(Lb + s8*512 + lane*8);
      half8v bh1 = *(const half8v*)(Lb + 4096 + s8*512 + lane*8);
      #pragma unroll
      for (int mt=0;mt<2;mt++){
        aH[mt][0] = __builtin_amdgcn_mfma_f32_16x16x32_f16(af[mt][s8], bh0, aH[mt][0], 0,0,0);
        aH[mt][1] = __builtin_amdgcn_mfma_f32_16x16x32_f16(af[mt][s8], bh1, aH[mt][1], 0,0,0);
      }
    }
    #pragma unroll
    for (int h=0;h<2;h++){
      int nt = nt0+h;
      int n = nt*16 + c16;
      float b1v = b1[n];
      float4 w2v = *(const float4*)(W2 + n*4);
      #pragma unroll
      for (int mt=0;mt<2;mt++){
        f32x4 acc = aH[mt][h];
        #pragma unroll
        for (int rr=0;rr<4;rr++){
          float hh = fmaxf(acc[rr]+b1v, 0.f);
          pacc[mt][rr][0]=fmaf(hh,w2v.x,pacc[mt][rr][0]);
          pacc[mt][rr][1]=fmaf(hh,w2v.y,pacc[mt][rr][1]);
          pacc[mt][rr][2]=fmaf(hh,w2v.z,pacc[mt][rr][2]);
          pacc[mt][rr][3]=fmaf(hh,w2v.w,pacc[mt][rr][3]);
        }
      }
    }
    __syncthreads();
    buf^=1;
  }
  #pragma unroll
  for (int mt=0;mt<2;mt++)
    #pragma unroll
    for (int rr=0;rr<4;rr++)
      #pragma unroll
      for (int c=0;c<4;c++){
        float v=pacc[mt][rr][c];
        v+=__shfl_xor(v,1); v+=__shfl_xor(v,2); v+=__shfl_xor(v,4); v+=__shfl_xor(v,8);
        pacc[mt][rr][c]=v;
      }
  if (c16==0){
    float bb0=b2[0], bb1=b2[1], bb2v=b2[2], bb3=b2[3];
    #pragma unroll
    for (int mt=0;mt<2;mt++)
      #pragma unroll
      for (int rr=0;rr<4;rr++){
        int pt_ = base + wave*32 + mt*16 + g*4 + rr;
        out_sigma[pt_] = pacc[mt][rr][0] + bb0;
        out_rgb[pt_*3+0] = sigm(pacc[mt][rr][1] + bb1);
        out_rgb[pt_*3+1] = sigm(pacc[mt][rr][2] + bb2v);
        out_rgb[pt_*3+2] = sigm(pacc[mt][rr][3] + bb3);
      }
  }
}

// --------- mask MLPs: two nets 3->256->1, sigmoid ---------
__global__ __launch_bounds__(256) void mask_kernel(
    const float* __restrict__ o, const float* __restrict__ dv, const float* __restrict__ z, int S,
    const float* __restrict__ Wa0, const float* __restrict__ ba0, const float* __restrict__ Wa1, const float* __restrict__ ba1,
    const float* __restrict__ Wb0, const float* __restrict__ bb0, const float* __restrict__ Wb1, const float* __restrict__ bb1,
    float* __restrict__ outA, float* __restrict__ outB)
{
  __shared__ __align__(16) float hA[PP][HH];
  __shared__ float pin[PP][4];
  __shared__ float part[PP][16];
  int t=threadIdx.x;
  int base=blockIdx.x*PP;
  if (t<PP){
    float pt[3];
    load_point(o,dv,z,base+t,S,1,pt,nullptr);
    pin[t][0]=pt[0]; pin[t][1]=pt[1]; pin[t][2]=pt[2];
  }
  __syncthreads();
  {
    float w0=Wa0[t], w1=Wa0[HH+t], w2=Wa0[2*HH+t], bb=ba0[t];
    #pragma unroll
    for (int p=0;p<PP;p++){
      float v = fmaf(pin[p][0],w0, fmaf(pin[p][1],w1, fmaf(pin[p][2],w2, bb)));
      hA[p][t]=fmaxf(v,0.f);
    }
  }
  __syncthreads();
  {
    int p=t>>4, g=t&15;
    float s=0.f;
    #pragma unroll
    for (int m=0;m<16;m++){ int j=g+16*m; s=fmaf(hA[p][j], Wa1[j], s); }
    part[p][g]=s;
  }
  __syncthreads();
  if (t<PP){
    float s=ba1[0];
    #pragma unroll
    for (int g=0;g<16;g++) s+=part[t][g];
    outA[base+t]=sigm(s);
  }
  __syncthreads();
  {
    float w0=Wb0[t], w1=Wb0[HH+t], w2=Wb0[2*HH+t], bb=bb0[t];
    #pragma unroll
    for (int p=0;p<PP;p++){
      float v = fmaf(pin[p][0],w0, fmaf(pin[p][1],w1, fmaf(pin[p][2],w2, bb)));
      hA[p][t]=fmaxf(v,0.f);
    }
  }
  __syncthreads();
  {
    int p=t>>4, g=t&15;
    float s=0.f;
    #pragma unroll
    for (int m=0;m<16;m++){ int j=g+16*m; s=fmaf(hA[p][j], Wb1[j], s); }
    part[p][g]=s;
  }
  __syncthreads();
  if (t<PP){
    float s=bb1[0];
    #pragma unroll
    for (int g=0;g<16;g++) s+=part[t][g];
    outB[base+t]=sigm(s);
  }
}

// --------- SDF up_sample + merge, one wave per ray ---------
__global__ __launch_bounds__(256) void upsample_wave_kernel(float* __restrict__ z,
    const float* __restrict__ sdf, const float* __restrict__ o, const float* __restrict__ dv,
    int S, float s, ZInit zi)
{
  __shared__ float zsh[4][128], ssh[4][128], csh[4][128], nzsh[4][16];
  int wave=threadIdx.x>>6, lane=threadIdx.x&63;
  int r=blockIdx.x*4+wave;
  float* zs=zsh[wave]; float* ss=ssh[wave]; float* cs=csh[wave]; float* nzs=nzsh[wave];
  for (int i=lane;i<S;i+=64){
    float zv;
    if (zi.on){
      float a=zi.loA[r], b=zi.hiA[r];
      zv = a + (b-a)*((float)i/(float)(S-1));
    } else zv = z[r*ZS+i];
    zs[i]=zv; ss[i]=sdf[r*S+i];
  }
  __syncthreads();
  float ox=o[r*3],oy=o[r*3+1],oz=o[r*3+2];
  float dx=dv[r*3],dy=dv[r*3+1],dz=dv[r*3+2];
  int M=S-1;
  auto alpha_at=[&](int k)->float{
    float z0=zs[k], z1=zs[k+1], s0=ss[k], s1=ss[k+1];
    float craw=(s1-s0)/(z1-z0+1e-5f);
    float cprev=(k>0)? (ss[k]-ss[k-1])/(zs[k]-zs[k-1]+1e-5f) : 0.f;
    float cv=fminf(craw,cprev);
    cv=fminf(fmaxf(cv,-1000.f),0.f);
    float px=ox+dx*z0, py=oy+dy*z0, pz=oz+dz*z0;
    float qx=ox+dx*z1, qy=oy+dy*z1, qz=oz+dz*z1;
    float r0=sqrtf(px*px+py*py+pz*pz);
    float r1=sqrtf(qx*qx+qy*qy+qz*qz);
    float inside=(r0<1.f||r1<1.f)?1.f:0.f;
    cv*=inside;
    float mid=0.5f*(s0+s1), dist=z1-z0;
    float pc=sigm((mid-0.5f*cv*dist)*s);
    float nc=sigm((mid+0.5f*cv*dist)*s);
    return (pc-nc+1e-5f)/(pc+1e-5f);
  };
  float al0=(lane<M)? alpha_at(lane):0.f;
  float al1=(lane+64<M)? alpha_at(lane+64):0.f;
  float f0=(lane<M)?(1.f-al0+1e-7f):1.f;
  float f1=(lane+64<M)?(1.f-al1+1e-7f):1.f;
  float ip0=iscan_prod(f0,lane);
  float tt=__shfl_up(ip0,1); float T0=(lane==0)?1.f:tt;
  float tot0=__shfl(ip0,63);
  float ip1=iscan_prod(f1,lane);
  float tu=__shfl_up(ip1,1); float T1=((lane==0)?1.f:tu)*tot0;
  float w0=(lane<M)? al0*T0+1e-5f:0.f;
  float w1=(lane+64<M)? al1*T1+1e-5f:0.f;
  float wsum=wave_sum(w0+w1);
  float inv=1.f/wsum;
  float is0=iscan_sum(w0,lane);
  float st0=__shfl(is0,63);
  float is1=iscan_sum(w1,lane)+st0;
  if (lane<M) cs[lane+1]=is0*inv;
  if (lane+64<M) cs[lane+64+1]=is1*inv;
  if (lane==0) cs[0]=0.f;
  __syncthreads();
  if (lane<16){
    float u=(lane+0.5f)/16.f;
    int lo=0,hi=S;
    while(lo<hi){ int m=(lo+hi)>>1; if(cs[m]<=u) lo=m+1; else hi=m; }
    int below=lo-1; below=below<0?0:(below>S-1?S-1:below);
    int above=lo>S-1?S-1:lo;
    float cb=cs[below], ca=cs[above], bb=zs[below], ba=zs[above];
    float dd=ca-cb; float den=(dd<1e-5f)?1.f:dd;
    nzs[lane]=bb+(u-cb)/den*(ba-bb);
  }
  __syncthreads();
  for (int i=lane;i<S;i+=64){
    float zi_=zs[i]; int cnt=0;
    #pragma unroll
    for (int j=0;j<16;j++) cnt += (nzs[j]<zi_)?1:0;
    z[r*ZS+i+cnt]=zi_;
  }
  if (lane<16){
    float v=nzs[lane]; int rk=0;
    #pragma unroll
    for (int j=0;j<16;j++) rk += ((nzs[j]<v)||(nzs[j]==v&&j<lane))?1:0;
    int lo=0,hi=S;
    while(lo<hi){ int m=(lo+hi)>>1; if(zs[m]<=v) lo=m+1; else hi=m; }
    z[r*ZS+lo+rk]=v;
  }
}

// --------- batched NeRF importance + merge, one wave per ray (4096 rays) ---------
__global__ __launch_bounds__(256) void nerf_imp_batch(float* __restrict__ zbuf,
    const float* __restrict__ sigma, const float* __restrict__ rLo, const float* __restrict__ rHi,
    int ptsA, int NRA)
{
  __shared__ float zsh[4][64], csh[4][64], nzsh[4][64];
  int wave=threadIdx.x>>6, lane=threadIdx.x&63;
  int r=blockIdx.x*4+wave;
  int S = (r<NRA)? 64 : 32;
  int n = S;
  int off = (r<NRA)? r*64 : ptsA + (r-NRA)*32;
  float* zs=zsh[wave]; float* cs=csh[wave]; float* nzs=nzsh[wave];
  if (lane<S){
    float a=rLo[r], b=rHi[r];
    zs[lane]= a + (b-a)*((float)lane/(float)(S-1));
  }
  __syncthreads();
  int M=S-1;
  float al=0.f;
  if (lane<M){
    float d_=zs[lane+1]-zs[lane];
    float sv=sigma[off+lane];
    al=1.f-__expf(-fmaxf(sv,0.f)*d_);
  }
  float f=(lane<M)?(1.f-al+1e-7f):1.f;
  float ip=iscan_prod(f,lane);
  float tt=__shfl_up(ip,1); float T=(lane==0)?1.f:tt;
  float w=(lane<M)? al*T+1e-5f:0.f;
  float wsum=wave_sum(w);
  float inv=1.f/wsum;
  float is=iscan_sum(w,lane);
  if (lane<M) cs[lane+1]=is*inv;
  if (lane==0) cs[0]=0.f;
  __syncthreads();
  if (lane<n){
    float u=(lane+0.5f)/(float)n;
    int lo=0,hi=S;
    while(lo<hi){ int m=(lo+hi)>>1; if(cs[m]<=u) lo=m+1; else hi=m; }
    int below=lo-1; below=below<0?0:(below>S-1?S-1:below);
    int above=lo>S-1?S-1:lo;
    float cb=cs[below], ca=cs[above], bb=zs[below], ba=zs[above];
    float dd=ca-cb; float den=(dd<1e-5f)?1.f:dd;
    nzs[lane]=bb+(u-cb)/den*(ba-bb);
  }
  __syncthreads();
  if (lane<S){
    float zi_=zs[lane]; int cnt=0;
    for (int j=0;j<n;j++) cnt += (nzs[j]<zi_)?1:0;
    zbuf[r*128+lane+cnt]=zi_;
  }
  if (lane<n){
    float v=nzs[lane]; int rk=0;
    for (int j=0;j<n;j++) rk += ((nzs[j]<v)||(nzs[j]==v&&j<lane))?1:0;
    int lo=0,hi=S;
    while(lo<hi){ int m=(lo+hi)>>1; if(zs[m]<=v) lo=m+1; else hi=m; }
    zbuf[r*128+lo+rk]=v;
  }
}

// --------- batched NeRF render, one wave per ray (4096 rays) ---------
__global__ __launch_bounds__(256) void nerf_render_batch(const float* __restrict__ zbuf,
    const float* __restrict__ sigma, const float* __restrict__ rgbp,
    int pts2A, int NRA,
    const float* __restrict__ mva, const float* __restrict__ mvb,
    float* __restrict__ c1b, float* __restrict__ m1b, float* __restrict__ m2b,
    float* __restrict__ cfb, float* __restrict__ czb, float* __restrict__ cbb)
{
  int wave=threadIdx.x>>6, lane=threadIdx.x&63;
  int r=blockIdx.x*4+wave;
  int S = (r<NRA)? 128 : 64;
  int off = (r<NRA)? r*128 : pts2A + (r-NRA)*64;
  const float* zr = zbuf + r*128;
  int domask = (r<1024);
  float a0=0.f,a1=0.f;
  if (lane<S){
    float d_=(lane<S-1)? zr[lane+1]-zr[lane] : SAMPLE_DIST;
    a0=1.f-__expf(-fmaxf(sigma[off+lane],0.f)*d_);
  }
  if (lane+64<S){
    int k=lane+64;
    float d_=(k<S-1)? zr[k+1]-zr[k] : SAMPLE_DIST;
    a1=1.f-__expf(-fmaxf(sigma[off+k],0.f)*d_);
  }
  float f0=(lane<S)?(1.f-a0+1e-7f):1.f;
  float f1=(lane+64<S)?(1.f-a1+1e-7f):1.f;
  float ip0=iscan_prod(f0,lane);
  float tt=__shfl_up(ip0,1); float T0=(lane==0)?1.f:tt;
  float tot0=__shfl(ip0,63);
  float ip1=iscan_prod(f1,lane);
  float tu=__shfl_up(ip1,1); float T1=((lane==0)?1.f:tu)*tot0;
  float w0=(lane<S)? a0*T0:0.f;
  float w1=(lane+64<S)? a1*T1:0.f;
  float c0=0,c1=0,c2=0,m1=0,m2=0;
  if (lane<S){
    int i0=off+lane;
    c0=w0*rgbp[i0*3]; c1=w0*rgbp[i0*3+1]; c2=w0*rgbp[i0*3+2];
    if (domask){ m1=w0*mva[i0]; m2=w0*mvb[i0]; }
  }
  if (lane+64<S){
    int i1=off+lane+64;
    c0=fmaf(w1,rgbp[i1*3],c0); c1=fmaf(w1,rgbp[i1*3+1],c1); c2=fmaf(w1,rgbp[i1*3+2],c2);
    if (domask){ m1=fmaf(w1,mva[i1],m1); m2=fmaf(w1,mvb[i1],m2); }
  }
  c0=wave_sum(c0); c1=wave_sum(c1); c2=wave_sum(c2);
  m1=wave_sum(m1); m2=wave_sum(m2);
  if (lane==0){
    int grp=r>>10, q=r&1023;
    float* outc = (grp==0)? c1b : (grp==1)? cfb : (grp==2)? czb : cbb;
    outc[q*3]=c0; outc[q*3+1]=c1; outc[q*3+2]=c2;
    if (grp==0){ m1b[q]=m1; m2b[q]=m2; }
  }
}

// --------- SDF render + hit/reflect/refract, one wave per ray (S=128) ---------
__global__ __launch_bounds__(256) void sdf_render_hit(const float* __restrict__ z,
    const float* __restrict__ sdf, const float* __restrict__ grad,
    const float* __restrict__ o, const float* __restrict__ dv,
    const float* __restrict__ svar,
    float* __restrict__ hitb, float* __restrict__ reflb, float* __restrict__ refrb)
{
  int wave=threadIdx.x>>6, lane=threadIdx.x&63;
  int r=blockIdx.x*4+wave;
  float inv_s=fminf(fmaxf(__expf(10.f*svar[0]),1e-6f),1e6f);
  float dx=dv[r*3],dy=dv[r*3+1],dz=dv[r*3+2];
  const float* zr=z+r*ZS;
  auto comp=[&](int k, float& alpha, float& midz, float& gx, float& gy, float& gz){
    float d_=(k<127)? zr[k+1]-zr[k] : SAMPLE_DIST;
    midz=zr[k]+0.5f*d_;
    int gi=(r*128+k)*3;
    gx=grad[gi]; gy=grad[gi+1]; gz=grad[gi+2];
    float tc=dx*gx+dy*gy+dz*gz;
    float ic=fminf(tc,0.f);
    float s_=sdf[r*128+k];
    float pc=sigm((s_-0.5f*ic*d_)*inv_s);
    float nc=sigm((s_+0.5f*ic*d_)*inv_s);
    alpha=fminf(fmaxf((pc-nc+1e-5f)/(pc+1e-5f),0.f),1.f);
  };
  float al0,mz0,g0x,g0y,g0z; comp(lane,al0,mz0,g0x,g0y,g0z);
  float al1,mz1,g1x,g1y,g1z; comp(lane+64,al1,mz1,g1x,g1y,g1z);
  float f0=1.f-al0+1e-7f, f1=1.f-al1+1e-7f;
  float ip0=iscan_prod(f0,lane);
  float tt=__shfl_up(ip0,1); float T0=(lane==0)?1.f:tt;
  float tot0=__shfl(ip0,63);
  float ip1=iscan_prod(f1,lane);
  float tu=__shfl_up(ip1,1); float T1=((lane==0)?1.f:tu)*tot0;
  float w0=al0*T0, w1=al1*T1;
  float n0=1.f/(sqrtf(g0x*g0x+g0y*g0y+g0z*g0z)+1e-12f);
  float n1=1.f/(sqrtf(g1x*g1x+g1y*g1y+g1z*g1z)+1e-12f);
  float dep=w0*mz0+w1*mz1;
  float sx=w0*n0*g0x+w1*n1*g1x;
  float sy=w0*n0*g0y+w1*n1*g1y;
  float sz=w0*n0*g0z+w1*n1*g1z;
  dep=wave_sum(dep); sx=wave_sum(sx); sy=wave_sum(sy); sz=wave_sum(sz);
  if (lane==0){
    float nn=1.f/(sqrtf(sx*sx+sy*sy+sz*sz)+1e-12f);
    float nx=sx*nn, ny=sy*nn, nz=sz*nn;
    hitb[r*3]  = o[r*3]  +dx*dep;
    hitb[r*3+1]= o[r*3+1]+dy*dep;
    hitb[r*3+2]= o[r*3+2]+dz*dep;
    float cs=dx*nx+dy*ny+dz*nz;
    if (cs>0.f){ nx=-nx; ny=-ny; nz=-nz; }
    float cosi=-(dx*nx+dy*ny+dz*nz);
    float rx=dx+2.f*cosi*nx, ry=dy+2.f*cosi*ny, rz=dz+2.f*cosi*nz;
    float eta=1.f/1.5f;
    float k=1.f-eta*eta*(1.f-cosi*cosi);
    float sq=sqrtf(fmaxf(k,0.f));
    float tx=eta*dx+(eta*cosi-sq)*nx;
    float ty=eta*dy+(eta*cosi-sq)*ny;
    float tz=eta*dz+(eta*cosi-sq)*nz;
    if (k<0.f){ tx=rx; ty=ry; tz=rz; }
    float rn=1.f/(sqrtf(rx*rx+ry*ry+rz*rz)+1e-12f);
    reflb[r*3]=rx*rn; reflb[r*3+1]=ry*rn; reflb[r*3+2]=rz*rn;
    float tn=1.f/(sqrtf(tx*tx+ty*ty+tz*tz)+1e-12f);
    refrb[r*3]=tx*tn; refrb[r*3+1]=ty*tn; refrb[r*3+2]=tz*tn;
  }
}

// --------- final composition ---------
__global__ void compose_kernel(const float* __restrict__ c1b, const float* __restrict__ m1b,
    const float* __restrict__ m2b, const float* __restrict__ cfb, const float* __restrict__ czb,
    const float* __restrict__ cbb, float* __restrict__ out)
{
  int r = blockIdx.x*blockDim.x + threadIdx.x;
  if (r >= NB) return;
  float m1=m1b[r], m2=m2b[r];
  #pragma unroll
  for (int c=0;c<3;c++){
    float v = c1b[r*3+c]*(1.f-m2) + cfb[r*3+c]*m2;
    float rz = 0.5f*czb[r*3+c] + 0.5f*cbb[r*3+c];
    out[r*3+c] = v*(1.f-m1) + rz*m1;
  }
}

extern "C" void kernel_launch(void* const* d_in, const int* in_sizes, int n_in,
                              void* d_out, int out_size, void* d_ws, size_t ws_size,
                              hipStream_t stream)
{
  const float* rays_o=(const float*)d_in[0];
  const float* rays_d=(const float*)d_in[1];
  const float* nearA =(const float*)d_in[2];
  const float* farA  =(const float*)d_in[3];
  const float* Ws0=(const float*)d_in[4];
  const float* bs0=(const float*)d_in[5];
  const float* Ws1=(const float*)d_in[6];
  const float* bs1=(const float*)d_in[7];
  const float* Ws2=(const float*)d_in[8];
  const float* bs2=(const float*)d_in[9];
  const float* svar=(const float*)d_in[10];
  const float* Wn0=(const float*)d_in[15];
  const float* bn0=(const float*)d_in[16];
  const float* Wn1=(const float*)d_in[17];
  const float* bn1=(const float*)d_in[18];
  const float* Wn2=(const float*)d_in[19];
  const float* bn2=(const float*)d_in[20];
  const float* Wrf0=(const float*)d_in[21];
  const float* brf0=(const float*)d_in[22];
  const float* Wrf1=(const float*)d_in[23];
  const float* brf1=(const float*)d_in[24];
  const float* Wrl0=(const float*)d_in[25];
  const float* brl0=(const float*)d_in[26];
  const float* Wrl1=(const float*)d_in[27];
  const float* brl1=(const float*)d_in[28];

  const int NRA   = 2048;
  const int PTS1A = 2048*64;
  const int PTS2A = 2048*128;

  float* ws=(float*)d_ws;
  float* zbuf = ws;  ws += 4096*128;
  float* sdfb = ws;  ws += 393216;
  float* uni  = ws;  ws += 1441792;
  float* gradb = uni;
  unsigned short* signsb = (unsigned short*)(uni + 393216);
  float* rgbp = uni;
  float* mv1  = ws;  ws += PTS1A;
  float* mv2  = ws;  ws += PTS1A;
  float* W1T  = ws;  ws += HH*HH;
  float* w2c  = ws;  ws += HH;
  float* rO   = ws;  ws += 4096*3;
  float* rD   = ws;  ws += 4096*3;
  float* rLo  = ws;  ws += 4096;
  float* rHi  = ws;  ws += 4096;
  float* hitb = ws;  ws += NB*3;
  float* reflb= ws;  ws += NB*3;
  float* refrb= ws;  ws += NB*3;
  float* c1b  = ws;  ws += NB*3;
  float* m1b  = ws;  ws += NB;
  float* m2b  = ws;  ws += NB;
  float* cfb  = ws;  ws += NB*3;
  float* czb  = ws;  ws += NB*3;
  float* cbb  = ws;  ws += NB*3;
  short* bfragN = (short*)ws; ws += HH*HH/2;
  short* bfragS = (short*)ws; ws += HH*HH/2;
  short* bfragT = (short*)ws; ws += HH*HH/2;

  const int RB = (NB+255)/256;
  const int WB = NB/4;

  ZInit ziNone{0,nullptr,nullptr,0.f,0.f,0.f,0.f};
  ZInit ziNF  {1,nearA,farA,0.f,0.f,0.f,0.f};

  prep_kernel<<<256,256,0,stream>>>(Ws1, Ws2, W1T, w2c);
  prep_bfrag_kernel<<<256,256,0,stream>>>(Wn1, bfragN);
  prep_bfrag_kernel<<<256,256,0,stream>>>(Ws1, bfragS);
  prep_bfrag_kernel<<<256,256,0,stream>>>(W1T, bfragT);

  // ---- stage 1: importance_sdf (main rays, zbuf stride 128) ----
  for (int i=0;i<4;i++){
    int S=64+16*i;
    float sscale=64.f*(float)(1<<i);
    sdf_mfma_kernel<<<NB*S/128,256,0,stream>>>(rays_o,rays_d,zbuf,S,0,ZS,(i==0?ziNF:ziNone),
        Ws0,bs0, bfragS,bs1, w2c,bs2, sdfb, nullptr);
    upsample_wave_kernel<<<WB,256,0,stream>>>(zbuf,sdfb,rays_o,rays_d,S,sscale,(i==0?ziNF:ziNone));
  }

  // ---- stage 2: render_sdf -> hit/refl/refr ----
  sdf_mfma_kernel<<<NB*128/128,256,0,stream>>>(rays_o,rays_d,zbuf,128,1,ZS,ziNone,
      Ws0,bs0, bfragS,bs1, w2c,bs2, sdfb, signsb);
  sdf_bwd_mfma_kernel<<<NB*128/128,256,0,stream>>>(rays_o,rays_d,zbuf, Ws0,bs0, signsb,
      bfragT, w2c, gradb);
  sdf_render_hit<<<WB,256,0,stream>>>(zbuf,sdfb,gradb,rays_o,rays_d,svar, hitb,reflb,refrb);

  // ---- batched NeRF: build 4096-virtual-ray table ----
  build_rays_kernel<<<16,256,0,stream>>>(rays_o,rays_d,nearA,farA, hitb,reflb,refrb, rO,rD,rLo,rHi);

  // pass 1: eval at analytic z (S=64 for rays<2048, S=32 else) -> sigma
  nerf_mfma_batch<<<(PTS1A + 2048*32)/128,256,0,stream>>>(rO,rD,rLo,rHi, zbuf,
      PTS1A, 6, 5, NRA, 0, 0,
      Wn0,bn0, bfragN,bn1, Wn2,bn2, sdfb,rgbp);
  // importance + merge -> zbuf (stride 128)
  nerf_imp_batch<<<4096/4,256,0,stream>>>(zbuf, sdfb, rLo,rHi, PTS1A, NRA);
  // pass 2: eval at midpoints of merged z (S=128 / 64) -> sigma+rgb
  nerf_mfma_batch<<<(PTS2A + 2048*64)/128,256,0,stream>>>(rO,rD,rLo,rHi, zbuf,
      PTS2A, 7, 6, NRA, 1, 1,
      Wn0,bn0, bfragN,bn1, Wn2,bn2, sdfb,rgbp);
  // masks (main rays only)
  mask_kernel<<<NB*128/PP,256,0,stream>>>(rays_o,rays_d,zbuf,128, Wrf0,brf0,Wrf1,brf1, Wrl0,brl0,Wrl1,brl1, mv1,mv2);
  // render all 4096 rays
  nerf_render_batch<<<4096/4,256,0,stream>>>(zbuf, sdfb, rgbp, PTS2A, NRA, mv1,mv2,
      c1b,m1b,m2b, cfb,czb,cbb);

  // ---- compose ----
  compose_kernel<<<RB,256,0,stream>>>(c1b,m1b,m2b,cfb,czb,cbb,(float*)d_out);
}

// Round 14
// 375.566 us; speedup vs baseline: 6.3800x; 1.0413x over previous
//
#include <hip/hip_runtime.h>

#define NB 1024
#define HH 256
#define ZS 128
#define PP 16
#define SAMPLE_DIST 0.03125f

typedef __attribute__((ext_vector_type(8))) _Float16 half8v;
typedef __attribute__((ext_vector_type(4))) float f32x4;

struct ZInit { int on; const float* loA; const float* hiA; float lo0,hi0,lo1,hi1; };

__device__ __forceinline__ float sigm(float x){ return 1.0f/(1.0f+__expf(-x)); }

// async global->LDS, 16B per lane; lds dest wave-uniform base (+lane*16 by HW)
__device__ __forceinline__ void gload_lds16(const void* g, void* l){
  __builtin_amdgcn_global_load_lds(
      (const __attribute__((address_space(1))) unsigned int*)g,
      (__attribute__((address_space(3))) unsigned int*)l, 16, 0, 0);
}

__device__ __forceinline__ float iscan_prod(float v, int lane){
  #pragma unroll
  for (int o=1;o<64;o<<=1){ float u=__shfl_up(v,o); if(lane>=o) v*=u; }
  return v;
}
__device__ __forceinline__ float iscan_sum(float v, int lane){
  #pragma unroll
  for (int o=1;o<64;o<<=1){ float u=__shfl_up(v,o); if(lane>=o) v+=u; }
  return v;
}
__device__ __forceinline__ float wave_sum(float v){
  #pragma unroll
  for (int o=1;o<64;o<<=1) v += __shfl_xor(v,o);
  return v;
}

// point loader with optional analytic z-init (sdf kernels, main rays)
__device__ __forceinline__ void load_point2(const float* __restrict__ o, const float* __restrict__ dv,
    const float* __restrict__ z, int idx, int S, int midflag, int zst, ZInit zi, float* pt, float* dir)
{
  int r = idx / S;
  int i = idx - r*S;
  float zz;
  if (zi.on){
    float a=zi.loA[r], b=zi.hiA[r];
    zz = a + (b-a)*((float)i/(float)(S-1));
    if (midflag){
      float z1 = a + (b-a)*((float)(i+1)/(float)(S-1));
      zz = (i < S-1) ? 0.5f*(zz+z1) : (zz + 0.5f*SAMPLE_DIST);
    }
  } else {
    const float* zr = z + r*zst;
    zz = zr[i];
    if (midflag) zz = (i < S-1) ? 0.5f*(zz + zr[i+1]) : (zz + 0.5f*SAMPLE_DIST);
  }
  #pragma unroll
  for (int c=0;c<3;c++){
    float dc = dv[r*3+c];
    pt[c] = o[r*3+c] + dc*zz;
    if (dir) dir[c] = dc;
  }
}

// legacy loader (mask kernel)
__device__ __forceinline__ void load_point(const float* __restrict__ o, const float* __restrict__ dv,
    const float* __restrict__ z, int idx, int S, int midflag, float* pt, float* dir)
{
  int r = idx / S;
  int i = idx - r*S;
  const float* zr = z + r*ZS;
  float zz = zr[i];
  if (midflag) zz = (i < S-1) ? 0.5f*(zz + zr[i+1]) : (zz + 0.5f*SAMPLE_DIST);
  #pragma unroll
  for (int c=0;c<3;c++){
    float dc = dv[r*3+c];
    pt[c] = o[r*3+c] + dc*zz;
    if (dir) dir[c] = dc;
  }
}

// --------- prep: transpose W_sdf1, extract col0 of W_sdf2 ---------
__global__ __launch_bounds__(256) void prep_kernel(const float* __restrict__ W1, const float* __restrict__ W2,
    float* __restrict__ W1T, float* __restrict__ w2col)
{
  int idx = blockIdx.x*256 + threadIdx.x;
  int j = idx >> 8, k = idx & 255;
  W1T[j*HH + k] = W1[k*HH + j];
  if (idx < HH) w2col[idx] = W2[idx*257];
}

// --------- prep: pack 256x256 f32 weight into f16 MFMA B-fragment order (standard) ---------
__global__ __launch_bounds__(256) void prep_bfrag_kernel(const float* __restrict__ W1,
    short* __restrict__ Bh)
{
  int idx = blockIdx.x*256 + threadIdx.x;
  int j = idx & 7;
  int lane = (idx>>3) & 63;
  int s = (idx>>9) & 7;
  int nt = idx >> 12;
  int k = s*32 + ((lane>>4)<<3) + j;
  int n = nt*16 + (lane&15);
  union { _Float16 h; short s; } u;
  u.h = (_Float16)W1[k*256 + n];
  Bh[idx] = u.s;
}

// --------- prep: rho-permuted B-fragment pack (for layer-0-MFMA consumers) ---------
// k = 32*s + 16*(j>>2) + 4*g + (j&3)
__global__ __launch_bounds__(256) void prep_bfrag_rho_kernel(const float* __restrict__ W1,
    short* __restrict__ Bh)
{
  int idx = blockIdx.x*256 + threadIdx.x;
  int j = idx & 7;
  int lane = (idx>>3) & 63;
  int s = (idx>>9) & 7;
  int nt = idx >> 12;
  int g = lane>>4;
  int k = 32*s + 16*(j>>2) + 4*g + (j&3);
  int n = nt*16 + (lane&15);
  union { _Float16 h; short s; } u;
  u.h = (_Float16)W1[k*256 + n];
  Bh[idx] = u.s;
}

// --------- prep: layer-0 A-fragment pack (16 tiles; k<6 weights, k==6 bias, else 0) ---------
__global__ __launch_bounds__(256) void prep_a0_kernel(const float* __restrict__ W0,
    const float* __restrict__ b0, short* __restrict__ A0h)
{
  int idx = blockIdx.x*256 + threadIdx.x;   // 8192
  if (idx >= 8192) return;
  int j = idx & 7;
  int lane = (idx>>3) & 63;
  int m = idx >> 9;
  int g = lane>>4, row = lane&15;
  int k = g*8 + j;
  int n0 = m*16 + row;
  float v = (k<6) ? W0[k*256 + n0] : (k==6 ? b0[n0] : 0.f);
  union { _Float16 h; short s; } u;
  u.h = (_Float16)v;
  A0h[idx] = u.s;
}

// --------- ray table build: 4096 virtual rays ---------
__global__ void build_rays_kernel(const float* __restrict__ ro, const float* __restrict__ rd,
    const float* __restrict__ nearA, const float* __restrict__ farA,
    const float* __restrict__ hit, const float* __restrict__ refl, const float* __restrict__ refr,
    float* __restrict__ rO, float* __restrict__ rD, float* __restrict__ rLo, float* __restrict__ rHi)
{
  int r = blockIdx.x*256 + threadIdx.x;
  if (r >= 4096) return;
  int m = r>>10, q = r&1023;
  const float* so; const float* sd; float lo,hi;
  if (m==0){ so=ro+q*3; sd=rd+q*3; lo=nearA[q]; hi=farA[q]; }
  else if (m==1){ so=hit+q*3; sd=refl+q*3; lo=0.05f; hi=3.7f; }
  else if (m==2){ so=hit+q*3; sd=refr+q*3; lo=0.f; hi=3.7f; }
  else { so=hit+q*3; sd=refr+q*3; lo=0.5f; hi=3.7f; }
  rO[r*3]=so[0]; rO[r*3+1]=so[1]; rO[r*3+2]=so[2];
  rD[r*3]=sd[0]; rD[r*3+1]=sd[1]; rD[r*3+2]=sd[2];
  rLo[r]=lo; rHi[r]=hi;
}

// --------- SDF value MLP via f16 MFMA (nt-pair LDS double buffer; round-13 form) ---------
__global__ __launch_bounds__(256) void sdf_mfma_kernel(
    const float* __restrict__ o, const float* __restrict__ dv, const float* __restrict__ z,
    int S, int midflag, int zst, ZInit zi,
    const float* __restrict__ W0, const float* __restrict__ b0,
    const short* __restrict__ Bh, const float* __restrict__ b1,
    const float* __restrict__ w2col, const float* __restrict__ b2,
    float* __restrict__ out_sdf, unsigned short* __restrict__ signs)
{
  __shared__ short ldsB[2][8192];
  __shared__ float xs[128][5];
  __shared__ float w0s[3*HH];
  __shared__ float b0s[HH];
  int t = threadIdx.x;
  int base = blockIdx.x*128;
  int wave=t>>6, lane=t&63, g=lane>>4, c16=lane&15;
  for (int i=t;i<3*HH;i+=256) w0s[i]=W0[i];
  b0s[t]=b0[t];
  if (t<128){
    float pt[3];
    load_point2(o,dv,z,base+t,S,midflag,zst,zi,pt,nullptr);
    xs[t][0]=pt[0]; xs[t][1]=pt[1]; xs[t][2]=pt[2];
  }
  {
    const char* gb = (const char*)Bh;
    #pragma unroll
    for (int c=0;c<4;c++){
      int ch = wave*4 + c;
      gload_lds16(gb + ch*1024 + lane*16, (void*)&ldsB[0][ch*512]);
    }
  }
  __syncthreads();
  half8v af[2][8];
  #pragma unroll
  for (int mt=0;mt<2;mt++){
    const float* xp = xs[wave*32 + mt*16 + c16];
    float x0=xp[0],x1=xp[1],x2=xp[2];
    #pragma unroll
    for (int s8=0;s8<8;s8++){
      int nb = s8*32 + g*8;
      union { _Float16 h[8]; half8v v; } uh;
      #pragma unroll
      for (int j=0;j<8;j++){
        int n=nb+j;
        float a=b0s[n];
        a=fmaf(x0,w0s[n],a);
        a=fmaf(x1,w0s[HH+n],a);
        a=fmaf(x2,w0s[2*HH+n],a);
        uh.h[j]=(_Float16)fmaxf(a,0.f);
      }
      af[mt][s8]=uh.v;
    }
  }
  float pacc[2][4];
  #pragma unroll
  for (int mt=0;mt<2;mt++){ pacc[mt][0]=0.f; pacc[mt][1]=0.f; pacc[mt][2]=0.f; pacc[mt][3]=0.f; }
  int buf=0;
  for (int ntp=0;ntp<8;ntp++){
    if (ntp<7){
      const char* gb = (const char*)(Bh + 2*(ntp+1)*4096);
      #pragma unroll
      for (int c=0;c<4;c++){
        int ch = wave*4 + c;
        gload_lds16(gb + ch*1024 + lane*16, (void*)&ldsB[buf^1][ch*512]);
      }
    }
    int nt0=2*ntp;
    f32x4 aH[2][2];
    #pragma unroll
    for (int mt=0;mt<2;mt++)
      #pragma unroll
      for (int h=0;h<2;h++) aH[mt][h]=(f32x4){0.f,0.f,0.f,0.f};
    const short* Lb = &ldsB[buf][0];
    #pragma unroll
    for (int s8=0;s8<8;s8++){
      half8v bh0 = *(const half8v*)(Lb + s8*512 + lane*8);
      half8v bh1 = *(const half8v*)(Lb + 4096 + s8*512 + lane*8);
      #pragma unroll
      for (int mt=0;mt<2;mt++){
        aH[mt][0] = __builtin_amdgcn_mfma_f32_16x16x32_f16(af[mt][s8], bh0, aH[mt][0], 0,0,0);
        aH[mt][1] = __builtin_amdgcn_mfma_f32_16x16x32_f16(af[mt][s8], bh1, aH[mt][1], 0,0,0);
      }
    }
    #pragma unroll
    for (int h=0;h<2;h++){
      int nt = nt0+h;
      int n = nt*16 + c16;
      float b1v = b1[n];
      float wv = w2col[n];
      #pragma unroll
      for (int mt=0;mt<2;mt++){
        f32x4 acc = aH[mt][h];
        #pragma unroll
        for (int rr=0;rr<4;rr++){
          float hv = acc[rr]+b1v;
          if (signs){
            unsigned long long m0 = __ballot(hv>0.f);
            if (c16==0) signs[(base+wave*32+mt*16+g*4+rr)*16+nt] = (unsigned short)(m0>>(16*g));
          }
          pacc[mt][rr]=fmaf(fmaxf(hv,0.f),wv,pacc[mt][rr]);
        }
      }
    }
    __syncthreads();
    buf^=1;
  }
  #pragma unroll
  for (int mt=0;mt<2;mt++)
    #pragma unroll
    for (int rr=0;rr<4;rr++){
      float v=pacc[mt][rr];
      v+=__shfl_xor(v,1); v+=__shfl_xor(v,2); v+=__shfl_xor(v,4); v+=__shfl_xor(v,8);
      pacc[mt][rr]=v;
    }
  if (c16==0){
    float bb2=b2[0];
    #pragma unroll
    for (int mt=0;mt<2;mt++)
      #pragma unroll
      for (int rr=0;rr<4;rr++)
        out_sdf[base + wave*32 + mt*16 + g*4 + rr] = pacc[mt][rr] + bb2;
  }
}

// --------- SDF backward via f16 MFMA (nt-pair LDS double buffer; round-13 form) ---------
__global__ __launch_bounds__(256) void sdf_bwd_mfma_kernel(
    const float* __restrict__ o, const float* __restrict__ dv, const float* __restrict__ z,
    const float* __restrict__ W0, const float* __restrict__ b0,
    const unsigned short* __restrict__ signs,
    const short* __restrict__ Th,
    const float* __restrict__ w2col,
    float* __restrict__ out_grad)
{
  __shared__ short ldsB[2][8192];
  __shared__ float xs[128][5];
  __shared__ float w0s[3*HH];
  __shared__ float b0s[HH];
  __shared__ _Float16 w2h_s[HH];
  int t = threadIdx.x;
  int base = blockIdx.x*128;
  int wave=t>>6, lane=t&63, g=lane>>4, c16=lane&15;
  for (int i=t;i<3*HH;i+=256) w0s[i]=W0[i];
  b0s[t]=b0[t];
  w2h_s[t]=(_Float16)w2col[t];
  if (t<128){
    float pt[3];
    ZInit zn{0,nullptr,nullptr,0,0,0,0};
    load_point2(o,dv,z,base+t,128,1,ZS,zn,pt,nullptr);
    xs[t][0]=pt[0]; xs[t][1]=pt[1]; xs[t][2]=pt[2];
  }
  {
    const char* gb = (const char*)Th;
    #pragma unroll
    for (int c=0;c<4;c++){
      int ch = wave*4 + c;
      gload_lds16(gb + ch*1024 + lane*16, (void*)&ldsB[0][ch*512]);
    }
  }
  __syncthreads();
  half8v af[2][8];
  #pragma unroll
  for (int mt=0;mt<2;mt++){
    int ptA = base + wave*32 + mt*16 + c16;
    #pragma unroll
    for (int s8=0;s8<8;s8++){
      int j0 = s8*32 + g*8;
      unsigned short wch = signs[ptA*16 + (j0>>4)];
      unsigned bits = ((unsigned)wch >> ((g&1)*8)) & 0xFFu;
      union { _Float16 h[8]; half8v v; } uh;
      #pragma unroll
      for (int jj=0;jj<8;jj++){
        bool on = (bits>>jj)&1u;
        uh.h[jj] = on ? w2h_s[j0+jj] : (_Float16)0.f;
      }
      af[mt][s8]=uh.v;
    }
  }
  float acc3[2][4][3];
  #pragma unroll
  for (int mt=0;mt<2;mt++)
    #pragma unroll
    for (int rr=0;rr<4;rr++){ acc3[mt][rr][0]=0.f; acc3[mt][rr][1]=0.f; acc3[mt][rr][2]=0.f; }
  int buf=0;
  for (int ntp=0;ntp<8;ntp++){
    if (ntp<7){
      const char* gb = (const char*)(Th + 2*(ntp+1)*4096);
      #pragma unroll
      for (int c=0;c<4;c++){
        int ch = wave*4 + c;
        gload_lds16(gb + ch*1024 + lane*16, (void*)&ldsB[buf^1][ch*512]);
      }
    }
    int nt0=2*ntp;
    f32x4 aH[2][2];
    #pragma unroll
    for (int mt=0;mt<2;mt++)
      #pragma unroll
      for (int h=0;h<2;h++) aH[mt][h]=(f32x4){0.f,0.f,0.f,0.f};
    const short* Lb = &ldsB[buf][0];
    #pragma unroll
    for (int s8=0;s8<8;s8++){
      half8v bh0 = *(const half8v*)(Lb + s8*512 + lane*8);
      half8v bh1 = *(const half8v*)(Lb + 4096 + s8*512 + lane*8);
      #pragma unroll
      for (int mt=0;mt<2;mt++){
        aH[mt][0] = __builtin_amdgcn_mfma_f32_16x16x32_f16(af[mt][s8], bh0, aH[mt][0], 0,0,0);
        aH[mt][1] = __builtin_amdgcn_mfma_f32_16x16x32_f16(af[mt][s8], bh1, aH[mt][1], 0,0,0);
      }
    }
    #pragma unroll
    for (int h=0;h<2;h++){
      int nt = nt0+h;
      int tn = nt*16 + c16;
      float w0a=w0s[tn], w0b=w0s[HH+tn], w0c=w0s[2*HH+tn], bb=b0s[tn];
      #pragma unroll
      for (int mt=0;mt<2;mt++){
        f32x4 acc = aH[mt][h];
        #pragma unroll
        for (int rr=0;rr<4;rr++){
          const float* xq = xs[wave*32 + mt*16 + g*4 + rr];
          float h0 = fmaf(xq[0],w0a, fmaf(xq[1],w0b, fmaf(xq[2],w0c, bb)));
          float dh0 = (h0>0.f) ? acc[rr] : 0.f;
          acc3[mt][rr][0]=fmaf(dh0,w0a,acc3[mt][rr][0]);
          acc3[mt][rr][1]=fmaf(dh0,w0b,acc3[mt][rr][1]);
          acc3[mt][rr][2]=fmaf(dh0,w0c,acc3[mt][rr][2]);
        }
      }
    }
    __syncthreads();
    buf^=1;
  }
  #pragma unroll
  for (int mt=0;mt<2;mt++)
    #pragma unroll
    for (int rr=0;rr<4;rr++)
      #pragma unroll
      for (int cc=0;cc<3;cc++){
        float v=acc3[mt][rr][cc];
        v+=__shfl_xor(v,1); v+=__shfl_xor(v,2); v+=__shfl_xor(v,4); v+=__shfl_xor(v,8);
        acc3[mt][rr][cc]=v;
      }
  if (c16==0){
    #pragma unroll
    for (int mt=0;mt<2;mt++)
      #pragma unroll
      for (int rr=0;rr<4;rr++){
        int pt_ = base + wave*32 + mt*16 + g*4 + rr;
        out_grad[pt_*3+0]=acc3[mt][rr][0];
        out_grad[pt_*3+1]=acc3[mt][rr][1];
        out_grad[pt_*3+2]=acc3[mt][rr][2];
      }
  }
}

// --------- batched NeRF MLP: layer-0 via MFMA (A0 in ldsB[1]); rho-packed layer-1 B ---------
__global__ __launch_bounds__(256) void nerf_mfma_batch(
    const float* __restrict__ rO, const float* __restrict__ rD,
    const float* __restrict__ rLo, const float* __restrict__ rHi,
    const float* __restrict__ zbuf, int ptsA, int lgSA, int lgSB, int NRA, int useZ, int midflag,
    const short* __restrict__ A0h, const short* __restrict__ Bh, const float* __restrict__ b1,
    const float* __restrict__ W2, const float* __restrict__ b2,
    float* __restrict__ out_sigma, float* __restrict__ out_rgb)
{
  __shared__ short ldsB[2][8192];
  int t = threadIdx.x;
  int base = blockIdx.x*128;
  int wave=t>>6, lane=t&63, g=lane>>4, c16=lane&15;
  // stage A0 (16KB) into ldsB[1] and first B nt-pair into ldsB[0]
  {
    const char* ga = (const char*)A0h;
    const char* gb = (const char*)Bh;
    #pragma unroll
    for (int c=0;c<4;c++){
      int ch = wave*4 + c;
      gload_lds16(ga + ch*1024 + lane*16, (void*)&ldsB[1][ch*512]);
      gload_lds16(gb + ch*1024 + lane*16, (void*)&ldsB[0][ch*512]);
    }
  }
  // per-lane point computation (registers)
  float xv[2][6];
  #pragma unroll
  for (int mt=0;mt<2;mt++){
    int idx = base + wave*32 + mt*16 + c16;
    int r,i,S;
    if (idx<ptsA){ r=idx>>lgSA; i=idx-(r<<lgSA); S=1<<lgSA; }
    else { int q=idx-ptsA; int rq=q>>lgSB; r=NRA+rq; i=q-(rq<<lgSB); S=1<<lgSB; }
    float zz;
    if (!useZ){
      float a=rLo[r], b=rHi[r];
      zz = a + (b-a)*((float)i/(float)(S-1));
      if (midflag){
        float z1 = a + (b-a)*((float)(i+1)/(float)(S-1));
        zz = (i<S-1)? 0.5f*(zz+z1) : (zz+0.5f*SAMPLE_DIST);
      }
    } else {
      const float* zr = zbuf + r*128;
      zz = zr[i];
      if (midflag) zz = (i<S-1)? 0.5f*(zz+zr[i+1]) : (zz+0.5f*SAMPLE_DIST);
    }
    #pragma unroll
    for (int c=0;c<3;c++){
      float dc=rD[r*3+c];
      xv[mt][c]   = rO[r*3+c] + dc*zz;
      xv[mt][3+c] = dc;
    }
  }
  // pack BX (k=0..5 inputs, k=6 -> 1.0 bias slot, k=7 zero; k>=8 lanes irrelevant since A0=0 there)
  half8v bx[2];
  #pragma unroll
  for (int mt=0;mt<2;mt++){
    union { _Float16 h[8]; half8v v; } u;
    #pragma unroll
    for (int c=0;c<6;c++) u.h[c]=(_Float16)xv[mt][c];
    u.h[6]=(_Float16)1.f; u.h[7]=(_Float16)0.f;
    bx[mt]=u.v;
  }
  __syncthreads();
  // layer 0 via MFMA: D0 = A0[m]*BX ; pack af with (m,rr)->(s8,j) bijection
  half8v af[2][8];
  #pragma unroll
  for (int s8=0;s8<8;s8++){
    half8v a0a = *(const half8v*)&ldsB[1][(2*s8)*512 + lane*8];
    half8v a0b = *(const half8v*)&ldsB[1][(2*s8+1)*512 + lane*8];
    f32x4 z4 = (f32x4){0.f,0.f,0.f,0.f};
    f32x4 da0 = __builtin_amdgcn_mfma_f32_16x16x32_f16(a0a, bx[0], z4, 0,0,0);
    f32x4 da1 = __builtin_amdgcn_mfma_f32_16x16x32_f16(a0a, bx[1], z4, 0,0,0);
    f32x4 db0 = __builtin_amdgcn_mfma_f32_16x16x32_f16(a0b, bx[0], z4, 0,0,0);
    f32x4 db1 = __builtin_amdgcn_mfma_f32_16x16x32_f16(a0b, bx[1], z4, 0,0,0);
    union { _Float16 h[8]; half8v v; } u0, u1;
    #pragma unroll
    for (int rr=0;rr<4;rr++){
      u0.h[rr]   = (_Float16)fmaxf(da0[rr],0.f);
      u0.h[4+rr] = (_Float16)fmaxf(db0[rr],0.f);
      u1.h[rr]   = (_Float16)fmaxf(da1[rr],0.f);
      u1.h[4+rr] = (_Float16)fmaxf(db1[rr],0.f);
    }
    af[0][s8]=u0.v; af[1][s8]=u1.v;
  }
  __syncthreads();   // ldsB[1] reads complete before ntp-loop prefetch overwrites it
  float pacc[2][4][4];
  #pragma unroll
  for (int mt=0;mt<2;mt++)
    #pragma unroll
    for (int rr=0;rr<4;rr++){ pacc[mt][rr][0]=0.f; pacc[mt][rr][1]=0.f; pacc[mt][rr][2]=0.f; pacc[mt][rr][3]=0.f; }
  int buf=0;
  for (int ntp=0;ntp<8;ntp++){
    if (ntp<7){
      const char* gb = (const char*)(Bh + 2*(ntp+1)*4096);
      #pragma unroll
      for (int c=0;c<4;c++){
        int ch = wave*4 + c;
        gload_lds16(gb + ch*1024 + lane*16, (void*)&ldsB[buf^1][ch*512]);
      }
    }
    int nt0=2*ntp;
    f32x4 aH[2][2];
    #pragma unroll
    for (int mt=0;mt<2;mt++)
      #pragma unroll
      for (int h=0;h<2;h++) aH[mt][h]=(f32x4){0.f,0.f,0.f,0.f};
    const short* Lb = &ldsB[buf][0];
    #pragma unroll
    for (int s8=0;s8<8;s8++){
      half8v bh0 = *(const half8v*)(Lb + s8*512 + lane*8);
      half8v bh1 = *(const half8v*)(Lb + 4096 + s8*512 + lane*8);
      #pragma unroll
      for (int mt=0;mt<2;mt++){
        aH[mt][0] = __builtin_amdgcn_mfma_f32_16x16x32_f16(af[mt][s8], bh0, aH[mt][0], 0,0,0);
        aH[mt][1] = __builtin_amdgcn_mfma_f32_16x16x32_f16(af[mt][s8], bh1, aH[mt][1], 0,0,0);
      }
    }
    #pragma unroll
    for (int h=0;h<2;h++){
      int nt = nt0+h;
      int n = nt*16 + c16;
      float b1v = b1[n];
      float4 w2v = *(const float4*)(W2 + n*4);
      #pragma unroll
      for (int mt=0;mt<2;mt++){
        f32x4 acc = aH[mt][h];
        #pragma unroll
        for (int rr=0;rr<4;rr++){
          float hh = fmaxf(acc[rr]+b1v, 0.f);
          pacc[mt][rr][0]=fmaf(hh,w2v.x,pacc[mt][rr][0]);
          pacc[mt][rr][1]=fmaf(hh,w2v.y,pacc[mt][rr][1]);
          pacc[mt][rr][2]=fmaf(hh,w2v.z,pacc[mt][rr][2]);
          pacc[mt][rr][3]=fmaf(hh,w2v.w,pacc[mt][rr][3]);
        }
      }
    }
    __syncthreads();
    buf^=1;
  }
  #pragma unroll
  for (int mt=0;mt<2;mt++)
    #pragma unroll
    for (int rr=0;rr<4;rr++)
      #pragma unroll
      for (int c=0;c<4;c++){
        float v=pacc[mt][rr][c];
        v+=__shfl_xor(v,1); v+=__shfl_xor(v,2); v+=__shfl_xor(v,4); v+=__shfl_xor(v,8);
        pacc[mt][rr][c]=v;
      }
  if (c16==0){
    float bb0=b2[0], bb1=b2[1], bb2v=b2[2], bb3=b2[3];
    #pragma unroll
    for (int mt=0;mt<2;mt++)
      #pragma unroll
      for (int rr=0;rr<4;rr++){
        int pt_ = base + wave*32 + mt*16 + g*4 + rr;
        out_sigma[pt_] = pacc[mt][rr][0] + bb0;
        out_rgb[pt_*3+0] = sigm(pacc[mt][rr][1] + bb1);
        out_rgb[pt_*3+1] = sigm(pacc[mt][rr][2] + bb2v);
        out_rgb[pt_*3+2] = sigm(pacc[mt][rr][3] + bb3);
      }
  }
}

// --------- mask MLPs: two nets 3->256->1, sigmoid ---------
__global__ __launch_bounds__(256) void mask_kernel(
    const float* __restrict__ o, const float* __restrict__ dv, const float* __restrict__ z, int S,
    const float* __restrict__ Wa0, const float* __restrict__ ba0, const float* __restrict__ Wa1, const float* __restrict__ ba1,
    const float* __restrict__ Wb0, const float* __restrict__ bb0, const float* __restrict__ Wb1, const float* __restrict__ bb1,
    float* __restrict__ outA, float* __restrict__ outB)
{
  __shared__ __align__(16) float hA[PP][HH];
  __shared__ float pin[PP][4];
  __shared__ float part[PP][16];
  int t=threadIdx.x;
  int base=blockIdx.x*PP;
  if (t<PP){
    float pt[3];
    load_point(o,dv,z,base+t,S,1,pt,nullptr);
    pin[t][0]=pt[0]; pin[t][1]=pt[1]; pin[t][2]=pt[2];
  }
  __syncthreads();
  {
    float w0=Wa0[t], w1=Wa0[HH+t], w2=Wa0[2*HH+t], bb=ba0[t];
    #pragma unroll
    for (int p=0;p<PP;p++){
      float v = fmaf(pin[p][0],w0, fmaf(pin[p][1],w1, fmaf(pin[p][2],w2, bb)));
      hA[p][t]=fmaxf(v,0.f);
    }
  }
  __syncthreads();
  {
    int p=t>>4, g=t&15;
    float s=0.f;
    #pragma unroll
    for (int m=0;m<16;m++){ int j=g+16*m; s=fmaf(hA[p][j], Wa1[j], s); }
    part[p][g]=s;
  }
  __syncthreads();
  if (t<PP){
    float s=ba1[0];
    #pragma unroll
    for (int g=0;g<16;g++) s+=part[t][g];
    outA[base+t]=sigm(s);
  }
  __syncthreads();
  {
    float w0=Wb0[t], w1=Wb0[HH+t], w2=Wb0[2*HH+t], bb=bb0[t];
    #pragma unroll
    for (int p=0;p<PP;p++){
      float v = fmaf(pin[p][0],w0, fmaf(pin[p][1],w1, fmaf(pin[p][2],w2, bb)));
      hA[p][t]=fmaxf(v,0.f);
    }
  }
  __syncthreads();
  {
    int p=t>>4, g=t&15;
    float s=0.f;
    #pragma unroll
    for (int m=0;m<16;m++){ int j=g+16*m; s=fmaf(hA[p][j], Wb1[j], s); }
    part[p][g]=s;
  }
  __syncthreads();
  if (t<PP){
    float s=bb1[0];
    #pragma unroll
    for (int g=0;g<16;g++) s+=part[t][g];
    outB[base+t]=sigm(s);
  }
}

// --------- SDF up_sample + merge, one wave per ray ---------
__global__ __launch_bounds__(256) void upsample_wave_kernel(float* __restrict__ z,
    const float* __restrict__ sdf, const float* __restrict__ o, const float* __restrict__ dv,
    int S, float s, ZInit zi)
{
  __shared__ float zsh[4][128], ssh[4][128], csh[4][128], nzsh[4][16];
  int wave=threadIdx.x>>6, lane=threadIdx.x&63;
  int r=blockIdx.x*4+wave;
  float* zs=zsh[wave]; float* ss=ssh[wave]; float* cs=csh[wave]; float* nzs=nzsh[wave];
  for (int i=lane;i<S;i+=64){
    float zv;
    if (zi.on){
      float a=zi.loA[r], b=zi.hiA[r];
      zv = a + (b-a)*((float)i/(float)(S-1));
    } else zv = z[r*ZS+i];
    zs[i]=zv; ss[i]=sdf[r*S+i];
  }
  __syncthreads();
  float ox=o[r*3],oy=o[r*3+1],oz=o[r*3+2];
  float dx=dv[r*3],dy=dv[r*3+1],dz=dv[r*3+2];
  int M=S-1;
  auto alpha_at=[&](int k)->float{
    float z0=zs[k], z1=zs[k+1], s0=ss[k], s1=ss[k+1];
    float craw=(s1-s0)/(z1-z0+1e-5f);
    float cprev=(k>0)? (ss[k]-ss[k-1])/(zs[k]-zs[k-1]+1e-5f) : 0.f;
    float cv=fminf(craw,cprev);
    cv=fminf(fmaxf(cv,-1000.f),0.f);
    float px=ox+dx*z0, py=oy+dy*z0, pz=oz+dz*z0;
    float qx=ox+dx*z1, qy=oy+dy*z1, qz=oz+dz*z1;
    float r0=sqrtf(px*px+py*py+pz*pz);
    float r1=sqrtf(qx*qx+qy*qy+qz*qz);
    float inside=(r0<1.f||r1<1.f)?1.f:0.f;
    cv*=inside;
    float mid=0.5f*(s0+s1), dist=z1-z0;
    float pc=sigm((mid-0.5f*cv*dist)*s);
    float nc=sigm((mid+0.5f*cv*dist)*s);
    return (pc-nc+1e-5f)/(pc+1e-5f);
  };
  float al0=(lane<M)? alpha_at(lane):0.f;
  float al1=(lane+64<M)? alpha_at(lane+64):0.f;
  float f0=(lane<M)?(1.f-al0+1e-7f):1.f;
  float f1=(lane+64<M)?(1.f-al1+1e-7f):1.f;
  float ip0=iscan_prod(f0,lane);
  float tt=__shfl_up(ip0,1); float T0=(lane==0)?1.f:tt;
  float tot0=__shfl(ip0,63);
  float ip1=iscan_prod(f1,lane);
  float tu=__shfl_up(ip1,1); float T1=((lane==0)?1.f:tu)*tot0;
  float w0=(lane<M)? al0*T0+1e-5f:0.f;
  float w1=(lane+64<M)? al1*T1+1e-5f:0.f;
  float wsum=wave_sum(w0+w1);
  float inv=1.f/wsum;
  float is0=iscan_sum(w0,lane);
  float st0=__shfl(is0,63);
  float is1=iscan_sum(w1,lane)+st0;
  if (lane<M) cs[lane+1]=is0*inv;
  if (lane+64<M) cs[lane+64+1]=is1*inv;
  if (lane==0) cs[0]=0.f;
  __syncthreads();
  if (lane<16){
    float u=(lane+0.5f)/16.f;
    int lo=0,hi=S;
    while(lo<hi){ int m=(lo+hi)>>1; if(cs[m]<=u) lo=m+1; else hi=m; }
    int below=lo-1; below=below<0?0:(below>S-1?S-1:below);
    int above=lo>S-1?S-1:lo;
    float cb=cs[below], ca=cs[above], bb=zs[below], ba=zs[above];
    float dd=ca-cb; float den=(dd<1e-5f)?1.f:dd;
    nzs[lane]=bb+(u-cb)/den*(ba-bb);
  }
  __syncthreads();
  for (int i=lane;i<S;i+=64){
    float zi_=zs[i]; int cnt=0;
    #pragma unroll
    for (int j=0;j<16;j++) cnt += (nzs[j]<zi_)?1:0;
    z[r*ZS+i+cnt]=zi_;
  }
  if (lane<16){
    float v=nzs[lane]; int rk=0;
    #pragma unroll
    for (int j=0;j<16;j++) rk += ((nzs[j]<v)||(nzs[j]==v&&j<lane))?1:0;
    int lo=0,hi=S;
    while(lo<hi){ int m=(lo+hi)>>1; if(zs[m]<=v) lo=m+1; else hi=m; }
    z[r*ZS+lo+rk]=v;
  }
}

// --------- batched NeRF importance + merge, one wave per ray (4096 rays) ---------
__global__ __launch_bounds__(256) void nerf_imp_batch(float* __restrict__ zbuf,
    const float* __restrict__ sigma, const float* __restrict__ rLo, const float* __restrict__ rHi,
    int ptsA, int NRA)
{
  __shared__ float zsh[4][64], csh[4][64], nzsh[4][64];
  int wave=threadIdx.x>>6, lane=threadIdx.x&63;
  int r=blockIdx.x*4+wave;
  int S = (r<NRA)? 64 : 32;
  int n = S;
  int off = (r<NRA)? r*64 : ptsA + (r-NRA)*32;
  float* zs=zsh[wave]; float* cs=csh[wave]; float* nzs=nzsh[wave];
  if (lane<S){
    float a=rLo[r], b=rHi[r];
    zs[lane]= a + (b-a)*((float)lane/(float)(S-1));
  }
  __syncthreads();
  int M=S-1;
  float al=0.f;
  if (lane<M){
    float d_=zs[lane+1]-zs[lane];
    float sv=sigma[off+lane];
    al=1.f-__expf(-fmaxf(sv,0.f)*d_);
  }
  float f=(lane<M)?(1.f-al+1e-7f):1.f;
  float ip=iscan_prod(f,lane);
  float tt=__shfl_up(ip,1); float T=(lane==0)?1.f:tt;
  float w=(lane<M)? al*T+1e-5f:0.f;
  float wsum=wave_sum(w);
  float inv=1.f/wsum;
  float is=iscan_sum(w,lane);
  if (lane<M) cs[lane+1]=is*inv;
  if (lane==0) cs[0]=0.f;
  __syncthreads();
  if (lane<n){
    float u=(lane+0.5f)/(float)n;
    int lo=0,hi=S;
    while(lo<hi){ int m=(lo+hi)>>1; if(cs[m]<=u) lo=m+1; else hi=m; }
    int below=lo-1; below=below<0?0:(below>S-1?S-1:below);
    int above=lo>S-1?S-1:lo;
    float cb=cs[below], ca=cs[above], bb=zs[below], ba=zs[above];
    float dd=ca-cb; float den=(dd<1e-5f)?1.f:dd;
    nzs[lane]=bb+(u-cb)/den*(ba-bb);
  }
  __syncthreads();
  if (lane<S){
    float zi_=zs[lane]; int cnt=0;
    for (int j=0;j<n;j++) cnt += (nzs[j]<zi_)?1:0;
    zbuf[r*128+lane+cnt]=zi_;
  }
  if (lane<n){
    float v=nzs[lane]; int rk=0;
    for (int j=0;j<n;j++) rk += ((nzs[j]<v)||(nzs[j]==v&&j<lane))?1:0;
    int lo=0,hi=S;
    while(lo<hi){ int m=(lo+hi)>>1; if(zs[m]<=v) lo=m+1; else hi=m; }
    zbuf[r*128+lo+rk]=v;
  }
}

// --------- batched NeRF render, one wave per ray (4096 rays) ---------
__global__ __launch_bounds__(256) void nerf_render_batch(const float* __restrict__ zbuf,
    const float* __restrict__ sigma, const float* __restrict__ rgbp,
    int pts2A, int NRA,
    const float* __restrict__ mva, const float* __restrict__ mvb,
    float* __restrict__ c1b, float* __restrict__ m1b, float* __restrict__ m2b,
    float* __restrict__ cfb, float* __restrict__ czb, float* __restrict__ cbb)
{
  int wave=threadIdx.x>>6, lane=threadIdx.x&63;
  int r=blockIdx.x*4+wave;
  int S = (r<NRA)? 128 : 64;
  int off = (r<NRA)? r*128 : pts2A + (r-NRA)*64;
  const float* zr = zbuf + r*128;
  int domask = (r<1024);
  float a0=0.f,a1=0.f;
  if (lane<S){
    float d_=(lane<S-1)? zr[lane+1]-zr[lane] : SAMPLE_DIST;
    a0=1.f-__expf(-fmaxf(sigma[off+lane],0.f)*d_);
  }
  if (lane+64<S){
    int k=lane+64;
    float d_=(k<S-1)? zr[k+1]-zr[k] : SAMPLE_DIST;
    a1=1.f-__expf(-fmaxf(sigma[off+k],0.f)*d_);
  }
  float f0=(lane<S)?(1.f-a0+1e-7f):1.f;
  float f1=(lane+64<S)?(1.f-a1+1e-7f):1.f;
  float ip0=iscan_prod(f0,lane);
  float tt=__shfl_up(ip0,1); float T0=(lane==0)?1.f:tt;
  float tot0=__shfl(ip0,63);
  float ip1=iscan_prod(f1,lane);
  float tu=__shfl_up(ip1,1); float T1=((lane==0)?1.f:tu)*tot0;
  float w0=(lane<S)? a0*T0:0.f;
  float w1=(lane+64<S)? a1*T1:0.f;
  float c0=0,c1=0,c2=0,m1=0,m2=0;
  if (lane<S){
    int i0=off+lane;
    c0=w0*rgbp[i0*3]; c1=w0*rgbp[i0*3+1]; c2=w0*rgbp[i0*3+2];
    if (domask){ m1=w0*mva[i0]; m2=w0*mvb[i0]; }
  }
  if (lane+64<S){
    int i1=off+lane+64;
    c0=fmaf(w1,rgbp[i1*3],c0); c1=fmaf(w1,rgbp[i1*3+1],c1); c2=fmaf(w1,rgbp[i1*3+2],c2);
    if (domask){ m1=fmaf(w1,mva[i1],m1); m2=fmaf(w1,mvb[i1],m2); }
  }
  c0=wave_sum(c0); c1=wave_sum(c1); c2=wave_sum(c2);
  m1=wave_sum(m1); m2=wave_sum(m2);
  if (lane==0){
    int grp=r>>10, q=r&1023;
    float* outc = (grp==0)? c1b : (grp==1)? cfb : (grp==2)? czb : cbb;
    outc[q*3]=c0; outc[q*3+1]=c1; outc[q*3+2]=c2;
    if (grp==0){ m1b[q]=m1; m2b[q]=m2; }
  }
}

// --------- SDF render + hit/reflect/refract, one wave per ray (S=128) ---------
__global__ __launch_bounds__(256) void sdf_render_hit(const float* __restrict__ z,
    const float* __restrict__ sdf, const float* __restrict__ grad,
    const float* __restrict__ o, const float* __restrict__ dv,
    const float* __restrict__ svar,
    float* __restrict__ hitb, float* __restrict__ reflb, float* __restrict__ refrb)
{
  int wave=threadIdx.x>>6, lane=threadIdx.x&63;
  int r=blockIdx.x*4+wave;
  float inv_s=fminf(fmaxf(__expf(10.f*svar[0]),1e-6f),1e6f);
  float dx=dv[r*3],dy=dv[r*3+1],dz=dv[r*3+2];
  const float* zr=z+r*ZS;
  auto comp=[&](int k, float& alpha, float& midz, float& gx, float& gy, float& gz){
    float d_=(k<127)? zr[k+1]-zr[k] : SAMPLE_DIST;
    midz=zr[k]+0.5f*d_;
    int gi=(r*128+k)*3;
    gx=grad[gi]; gy=grad[gi+1]; gz=grad[gi+2];
    float tc=dx*gx+dy*gy+dz*gz;
    float ic=fminf(tc,0.f);
    float s_=sdf[r*128+k];
    float pc=sigm((s_-0.5f*ic*d_)*inv_s);
    float nc=sigm((s_+0.5f*ic*d_)*inv_s);
    alpha=fminf(fmaxf((pc-nc+1e-5f)/(pc+1e-5f),0.f),1.f);
  };
  float al0,mz0,g0x,g0y,g0z; comp(lane,al0,mz0,g0x,g0y,g0z);
  float al1,mz1,g1x,g1y,g1z; comp(lane+64,al1,mz1,g1x,g1y,g1z);
  float f0=1.f-al0+1e-7f, f1=1.f-al1+1e-7f;
  float ip0=iscan_prod(f0,lane);
  float tt=__shfl_up(ip0,1); float T0=(lane==0)?1.f:tt;
  float tot0=__shfl(ip0,63);
  float ip1=iscan_prod(f1,lane);
  float tu=__shfl_up(ip1,1); float T1=((lane==0)?1.f:tu)*tot0;
  float w0=al0*T0, w1=al1*T1;
  float n0=1.f/(sqrtf(g0x*g0x+g0y*g0y+g0z*g0z)+1e-12f);
  float n1=1.f/(sqrtf(g1x*g1x+g1y*g1y+g1z*g1z)+1e-12f);
  float dep=w0*mz0+w1*mz1;
  float sx=w0*n0*g0x+w1*n1*g1x;
  float sy=w0*n0*g0y+w1*n1*g1y;
  float sz=w0*n0*g0z+w1*n1*g1z;
  dep=wave_sum(dep); sx=wave_sum(sx); sy=wave_sum(sy); sz=wave_sum(sz);
  if (lane==0){
    float nn=1.f/(sqrtf(sx*sx+sy*sy+sz*sz)+1e-12f);
    float nx=sx*nn, ny=sy*nn, nz=sz*nn;
    hitb[r*3]  = o[r*3]  +dx*dep;
    hitb[r*3+1]= o[r*3+1]+dy*dep;
    hitb[r*3+2]= o[r*3+2]+dz*dep;
    float cs=dx*nx+dy*ny+dz*nz;
    if (cs>0.f){ nx=-nx; ny=-ny; nz=-nz; }
    float cosi=-(dx*nx+dy*ny+dz*nz);
    float rx=dx+2.f*cosi*nx, ry=dy+2.f*cosi*ny, rz=dz+2.f*cosi*nz;
    float eta=1.f/1.5f;
    float k=1.f-eta*eta*(1.f-cosi*cosi);
    float sq=sqrtf(fmaxf(k,0.f));
    float tx=eta*dx+(eta*cosi-sq)*nx;
    float ty=eta*dy+(eta*cosi-sq)*ny;
    float tz=eta*dz+(eta*cosi-sq)*nz;
    if (k<0.f){ tx=rx; ty=ry; tz=rz; }
    float rn=1.f/(sqrtf(rx*rx+ry*ry+rz*rz)+1e-12f);
    reflb[r*3]=rx*rn; reflb[r*3+1]=ry*rn; reflb[r*3+2]=rz*rn;
    float tn=1.f/(sqrtf(tx*tx+ty*ty+tz*tz)+1e-12f);
    refrb[r*3]=tx*tn; refrb[r*3+1]=ty*tn; refrb[r*3+2]=tz*tn;
  }
}

// --------- final composition ---------
__global__ void compose_kernel(const float* __restrict__ c1b, const float* __restrict__ m1b,
    const float* __restrict__ m2b, const float* __restrict__ cfb, const float* __restrict__ czb,
    const float* __restrict__ cbb, float* __restrict__ out)
{
  int r = blockIdx.x*blockDim.x + threadIdx.x;
  if (r >= NB) return;
  float m1=m1b[r], m2=m2b[r];
  #pragma unroll
  for (int c=0;c<3;c++){
    float v = c1b[r*3+c]*(1.f-m2) + cfb[r*3+c]*m2;
    float rz = 0.5f*czb[r*3+c] + 0.5f*cbb[r*3+c];
    out[r*3+c] = v*(1.f-m1) + rz*m1;
  }
}

extern "C" void kernel_launch(void* const* d_in, const int* in_sizes, int n_in,
                              void* d_out, int out_size, void* d_ws, size_t ws_size,
                              hipStream_t stream)
{
  const float* rays_o=(const float*)d_in[0];
  const float* rays_d=(const float*)d_in[1];
  const float* nearA =(const float*)d_in[2];
  const float* farA  =(const float*)d_in[3];
  const float* Ws0=(const float*)d_in[4];
  const float* bs0=(const float*)d_in[5];
  const float* Ws1=(const float*)d_in[6];
  const float* bs1=(const float*)d_in[7];
  const float* Ws2=(const float*)d_in[8];
  const float* bs2=(const float*)d_in[9];
  const float* svar=(const float*)d_in[10];
  const float* Wn0=(const float*)d_in[15];
  const float* bn0=(const float*)d_in[16];
  const float* Wn1=(const float*)d_in[17];
  const float* bn1=(const float*)d_in[18];
  const float* Wn2=(const float*)d_in[19];
  const float* bn2=(const float*)d_in[20];
  const float* Wrf0=(const float*)d_in[21];
  const float* brf0=(const float*)d_in[22];
  const float* Wrf1=(const float*)d_in[23];
  const float* brf1=(const float*)d_in[24];
  const float* Wrl0=(const float*)d_in[25];
  const float* brl0=(const float*)d_in[26];
  const float* Wrl1=(const float*)d_in[27];
  const float* brl1=(const float*)d_in[28];

  const int NRA   = 2048;
  const int PTS1A = 2048*64;
  const int PTS2A = 2048*128;

  float* ws=(float*)d_ws;
  float* zbuf = ws;  ws += 4096*128;
  float* sdfb = ws;  ws += 393216;
  float* uni  = ws;  ws += 1441792;
  float* gradb = uni;
  unsigned short* signsb = (unsigned short*)(uni + 393216);
  float* rgbp = uni;
  float* mv1  = ws;  ws += PTS1A;
  float* mv2  = ws;  ws += PTS1A;
  float* W1T  = ws;  ws += HH*HH;
  float* w2c  = ws;  ws += HH;
  float* rO   = ws;  ws += 4096*3;
  float* rD   = ws;  ws += 4096*3;
  float* rLo  = ws;  ws += 4096;
  float* rHi  = ws;  ws += 4096;
  float* hitb = ws;  ws += NB*3;
  float* reflb= ws;  ws += NB*3;
  float* refrb= ws;  ws += NB*3;
  float* c1b  = ws;  ws += NB*3;
  float* m1b  = ws;  ws += NB;
  float* m2b  = ws;  ws += NB;
  float* cfb  = ws;  ws += NB*3;
  float* czb  = ws;  ws += NB*3;
  float* cbb  = ws;  ws += NB*3;
  short* bfragN = (short*)ws; ws += HH*HH/2;
  short* bfragS = (short*)ws; ws += HH*HH/2;
  short* bfragT = (short*)ws; ws += HH*HH/2;
  short* a0N    = (short*)ws; ws += 4096;     // 8192 f16 = 16KB

  const int RB = (NB+255)/256;
  const int WB = NB/4;

  ZInit ziNone{0,nullptr,nullptr,0.f,0.f,0.f,0.f};
  ZInit ziNF  {1,nearA,farA,0.f,0.f,0.f,0.f};

  prep_kernel<<<256,256,0,stream>>>(Ws1, Ws2, W1T, w2c);
  prep_bfrag_rho_kernel<<<256,256,0,stream>>>(Wn1, bfragN);
  prep_bfrag_kernel<<<256,256,0,stream>>>(Ws1, bfragS);
  prep_bfrag_kernel<<<256,256,0,stream>>>(W1T, bfragT);
  prep_a0_kernel<<<32,256,0,stream>>>(Wn0, bn0, a0N);

  // ---- stage 1: importance_sdf (main rays, zbuf stride 128) ----
  for (int i=0;i<4;i++){
    int S=64+16*i;
    float sscale=64.f*(float)(1<<i);
    sdf_mfma_kernel<<<NB*S/128,256,0,stream>>>(rays_o,rays_d,zbuf,S,0,ZS,(i==0?ziNF:ziNone),
        Ws0,bs0, bfragS,bs1, w2c,bs2, sdfb, nullptr);
    upsample_wave_kernel<<<WB,256,0,stream>>>(zbuf,sdfb,rays_o,rays_d,S,sscale,(i==0?ziNF:ziNone));
  }

  // ---- stage 2: render_sdf -> hit/refl/refr ----
  sdf_mfma_kernel<<<NB*128/128,256,0,stream>>>(rays_o,rays_d,zbuf,128,1,ZS,ziNone,
      Ws0,bs0, bfragS,bs1, w2c,bs2, sdfb, signsb);
  sdf_bwd_mfma_kernel<<<NB*128/128,256,0,stream>>>(rays_o,rays_d,zbuf, Ws0,bs0, signsb,
      bfragT, w2c, gradb);
  sdf_render_hit<<<WB,256,0,stream>>>(zbuf,sdfb,gradb,rays_o,rays_d,svar, hitb,reflb,refrb);

  // ---- batched NeRF: build 4096-virtual-ray table ----
  build_rays_kernel<<<16,256,0,stream>>>(rays_o,rays_d,nearA,farA, hitb,reflb,refrb, rO,rD,rLo,rHi);

  // pass 1: eval at analytic z (S=64 for rays<2048, S=32 else) -> sigma
  nerf_mfma_batch<<<(PTS1A + 2048*32)/128,256,0,stream>>>(rO,rD,rLo,rHi, zbuf,
      PTS1A, 6, 5, NRA, 0, 0,
      a0N, bfragN, bn1, Wn2,bn2, sdfb,rgbp);
  // importance + merge -> zbuf (stride 128)
  nerf_imp_batch<<<4096/4,256,0,stream>>>(zbuf, sdfb, rLo,rHi, PTS1A, NRA);
  // pass 2: eval at midpoints of merged z (S=128 / 64) -> sigma+rgb
  nerf_mfma_batch<<<(PTS2A + 2048*64)/128,256,0,stream>>>(rO,rD,rLo,rHi, zbuf,
      PTS2A, 7, 6, NRA, 1, 1,
      a0N, bfragN, bn1, Wn2,bn2, sdfb,rgbp);
  // masks (main rays only)
  mask_kernel<<<NB*128/PP,256,0,stream>>>(rays_o,rays_d,zbuf,128, Wrf0,brf0,Wrf1,brf1, Wrl0,brl0,Wrl1,brl1, mv1,mv2);
  // render all 4096 rays
  nerf_render_batch<<<4096/4,256,0,stream>>>(zbuf, sdfb, rgbp, PTS2A, NRA, mv1,mv2,
      c1b,m1b,m2b, cfb,czb,cbb);

  // ---- compose ----
  compose_kernel<<<RB,256,0,stream>>>(c1b,m1b,m2b,cfb,czb,cbb,(float*)d_out);
}

// Round 16
// 368.309 us; speedup vs baseline: 6.5057x; 1.0197x over previous
//
#include <hip/hip_runtime.h>

#define NB 1024
#define HH 256
#define ZS 128
#define PP 16
#define SAMPLE_DIST 0.03125f

typedef __attribute__((ext_vector_type(8))) _Float16 half8v;
typedef __attribute__((ext_vector_type(4))) float f32x4;

struct ZInit { int on; const float* loA; const float* hiA; float lo0,hi0,lo1,hi1; };

__device__ __forceinline__ float sigm(float x){ return 1.0f/(1.0f+__expf(-x)); }

// async global->LDS, 16B per lane; lds dest wave-uniform base (+lane*16 by HW)
__device__ __forceinline__ void gload_lds16(const void* g, void* l){
  __builtin_amdgcn_global_load_lds(
      (const __attribute__((address_space(1))) unsigned int*)g,
      (__attribute__((address_space(3))) unsigned int*)l, 16, 0, 0);
}

__device__ __forceinline__ float iscan_prod(float v, int lane){
  #pragma unroll
  for (int o=1;o<64;o<<=1){ float u=__shfl_up(v,o); if(lane>=o) v*=u; }
  return v;
}
__device__ __forceinline__ float iscan_sum(float v, int lane){
  #pragma unroll
  for (int o=1;o<64;o<<=1){ float u=__shfl_up(v,o); if(lane>=o) v+=u; }
  return v;
}
__device__ __forceinline__ float wave_sum(float v){
  #pragma unroll
  for (int o=1;o<64;o<<=1) v += __shfl_xor(v,o);
  return v;
}

// point loader with optional analytic z-init (sdf kernels, main rays)
__device__ __forceinline__ void load_point2(const float* __restrict__ o, const float* __restrict__ dv,
    const float* __restrict__ z, int idx, int S, int midflag, int zst, ZInit zi, float* pt, float* dir)
{
  int r = idx / S;
  int i = idx - r*S;
  float zz;
  if (zi.on){
    float a=zi.loA[r], b=zi.hiA[r];
    zz = a + (b-a)*((float)i/(float)(S-1));
    if (midflag){
      float z1 = a + (b-a)*((float)(i+1)/(float)(S-1));
      zz = (i < S-1) ? 0.5f*(zz+z1) : (zz + 0.5f*SAMPLE_DIST);
    }
  } else {
    const float* zr = z + r*zst;
    zz = zr[i];
    if (midflag) zz = (i < S-1) ? 0.5f*(zz + zr[i+1]) : (zz + 0.5f*SAMPLE_DIST);
  }
  #pragma unroll
  for (int c=0;c<3;c++){
    float dc = dv[r*3+c];
    pt[c] = o[r*3+c] + dc*zz;
    if (dir) dir[c] = dc;
  }
}

// legacy loader (mask kernel)
__device__ __forceinline__ void load_point(const float* __restrict__ o, const float* __restrict__ dv,
    const float* __restrict__ z, int idx, int S, int midflag, float* pt, float* dir)
{
  int r = idx / S;
  int i = idx - r*S;
  const float* zr = z + r*ZS;
  float zz = zr[i];
  if (midflag) zz = (i < S-1) ? 0.5f*(zz + zr[i+1]) : (zz + 0.5f*SAMPLE_DIST);
  #pragma unroll
  for (int c=0;c<3;c++){
    float dc = dv[r*3+c];
    pt[c] = o[r*3+c] + dc*zz;
    if (dir) dir[c] = dc;
  }
}

// --------- prep: transpose W_sdf1, extract col0 of W_sdf2 ---------
__global__ __launch_bounds__(256) void prep_kernel(const float* __restrict__ W1, const float* __restrict__ W2,
    float* __restrict__ W1T, float* __restrict__ w2col)
{
  int idx = blockIdx.x*256 + threadIdx.x;
  int j = idx >> 8, k = idx & 255;
  W1T[j*HH + k] = W1[k*HH + j];
  if (idx < HH) w2col[idx] = W2[idx*257];
}

// --------- prep: pack 256x256 f32 weight into f16 MFMA B-fragment order (standard) ---------
__global__ __launch_bounds__(256) void prep_bfrag_kernel(const float* __restrict__ W1,
    short* __restrict__ Bh)
{
  int idx = blockIdx.x*256 + threadIdx.x;
  int j = idx & 7;
  int lane = (idx>>3) & 63;
  int s = (idx>>9) & 7;
  int nt = idx >> 12;
  int k = s*32 + ((lane>>4)<<3) + j;
  int n = nt*16 + (lane&15);
  union { _Float16 h; short s; } u;
  u.h = (_Float16)W1[k*256 + n];
  Bh[idx] = u.s;
}

// --------- prep: rho-permuted B-fragment pack (for layer-0-MFMA consumers) ---------
// k = 32*s + 16*(j>>2) + 4*g + (j&3)
__global__ __launch_bounds__(256) void prep_bfrag_rho_kernel(const float* __restrict__ W1,
    short* __restrict__ Bh)
{
  int idx = blockIdx.x*256 + threadIdx.x;
  int j = idx & 7;
  int lane = (idx>>3) & 63;
  int s = (idx>>9) & 7;
  int nt = idx >> 12;
  int g = lane>>4;
  int k = 32*s + 16*(j>>2) + 4*g + (j&3);
  int n = nt*16 + (lane&15);
  union { _Float16 h; short s; } u;
  u.h = (_Float16)W1[k*256 + n];
  Bh[idx] = u.s;
}

// --------- prep: layer-0 A-fragment pack (16 tiles; k<kin weights, k==kin bias, else 0) ---------
__global__ __launch_bounds__(256) void prep_a0_kernel(const float* __restrict__ W0,
    const float* __restrict__ b0, short* __restrict__ A0h, int kin)
{
  int idx = blockIdx.x*256 + threadIdx.x;   // 8192
  if (idx >= 8192) return;
  int j = idx & 7;
  int lane = (idx>>3) & 63;
  int m = idx >> 9;
  int g = lane>>4, row = lane&15;
  int k = g*8 + j;
  int n0 = m*16 + row;
  float v = (k<kin) ? W0[k*256 + n0] : (k==kin ? b0[n0] : 0.f);
  union { _Float16 h; short s; } u;
  u.h = (_Float16)v;
  A0h[idx] = u.s;
}

// --------- ray table build: 4096 virtual rays ---------
__global__ void build_rays_kernel(const float* __restrict__ ro, const float* __restrict__ rd,
    const float* __restrict__ nearA, const float* __restrict__ farA,
    const float* __restrict__ hit, const float* __restrict__ refl, const float* __restrict__ refr,
    float* __restrict__ rO, float* __restrict__ rD, float* __restrict__ rLo, float* __restrict__ rHi)
{
  int r = blockIdx.x*256 + threadIdx.x;
  if (r >= 4096) return;
  int m = r>>10, q = r&1023;
  const float* so; const float* sd; float lo,hi;
  if (m==0){ so=ro+q*3; sd=rd+q*3; lo=nearA[q]; hi=farA[q]; }
  else if (m==1){ so=hit+q*3; sd=refl+q*3; lo=0.05f; hi=3.7f; }
  else if (m==2){ so=hit+q*3; sd=refr+q*3; lo=0.f; hi=3.7f; }
  else { so=hit+q*3; sd=refr+q*3; lo=0.5f; hi=3.7f; }
  rO[r*3]=so[0]; rO[r*3+1]=so[1]; rO[r*3+2]=so[2];
  rD[r*3]=sd[0]; rD[r*3+1]=sd[1]; rD[r*3+2]=sd[2];
  rLo[r]=lo; rHi[r]=hi;
}

// --------- SDF value MLP via f16 MFMA (scalar f32 layer-0; round-14 proven) ---------
__global__ __launch_bounds__(256) void sdf_mfma_kernel(
    const float* __restrict__ o, const float* __restrict__ dv, const float* __restrict__ z,
    int S, int midflag, int zst, ZInit zi,
    const float* __restrict__ W0, const float* __restrict__ b0,
    const short* __restrict__ Bh, const float* __restrict__ b1,
    const float* __restrict__ w2col, const float* __restrict__ b2,
    float* __restrict__ out_sdf, unsigned short* __restrict__ signs)
{
  __shared__ short ldsB[2][8192];
  __shared__ float xs[128][5];
  __shared__ float w0s[3*HH];
  __shared__ float b0s[HH];
  int t = threadIdx.x;
  int base = blockIdx.x*128;
  int wave=t>>6, lane=t&63, g=lane>>4, c16=lane&15;
  for (int i=t;i<3*HH;i+=256) w0s[i]=W0[i];
  b0s[t]=b0[t];
  if (t<128){
    float pt[3];
    load_point2(o,dv,z,base+t,S,midflag,zst,zi,pt,nullptr);
    xs[t][0]=pt[0]; xs[t][1]=pt[1]; xs[t][2]=pt[2];
  }
  {
    const char* gb = (const char*)Bh;
    #pragma unroll
    for (int c=0;c<4;c++){
      int ch = wave*4 + c;
      gload_lds16(gb + ch*1024 + lane*16, (void*)&ldsB[0][ch*512]);
    }
  }
  __syncthreads();
  half8v af[2][8];
  #pragma unroll
  for (int mt=0;mt<2;mt++){
    const float* xp = xs[wave*32 + mt*16 + c16];
    float x0=xp[0],x1=xp[1],x2=xp[2];
    #pragma unroll
    for (int s8=0;s8<8;s8++){
      int nb = s8*32 + g*8;
      union { _Float16 h[8]; half8v v; } uh;
      #pragma unroll
      for (int j=0;j<8;j++){
        int n=nb+j;
        float a=b0s[n];
        a=fmaf(x0,w0s[n],a);
        a=fmaf(x1,w0s[HH+n],a);
        a=fmaf(x2,w0s[2*HH+n],a);
        uh.h[j]=(_Float16)fmaxf(a,0.f);
      }
      af[mt][s8]=uh.v;
    }
  }
  float pacc[2][4];
  #pragma unroll
  for (int mt=0;mt<2;mt++){ pacc[mt][0]=0.f; pacc[mt][1]=0.f; pacc[mt][2]=0.f; pacc[mt][3]=0.f; }
  int buf=0;
  for (int ntp=0;ntp<8;ntp++){
    if (ntp<7){
      const char* gb = (const char*)(Bh + 2*(ntp+1)*4096);
      #pragma unroll
      for (int c=0;c<4;c++){
        int ch = wave*4 + c;
        gload_lds16(gb + ch*1024 + lane*16, (void*)&ldsB[buf^1][ch*512]);
      }
    }
    int nt0=2*ntp;
    f32x4 aH[2][2];
    #pragma unroll
    for (int mt=0;mt<2;mt++)
      #pragma unroll
      for (int h=0;h<2;h++) aH[mt][h]=(f32x4){0.f,0.f,0.f,0.f};
    const short* Lb = &ldsB[buf][0];
    #pragma unroll
    for (int s8=0;s8<8;s8++){
      half8v bh0 = *(const half8v*)(Lb + s8*512 + lane*8);
      half8v bh1 = *(const half8v*)(Lb + 4096 + s8*512 + lane*8);
      #pragma unroll
      for (int mt=0;mt<2;mt++){
        aH[mt][0] = __builtin_amdgcn_mfma_f32_16x16x32_f16(af[mt][s8], bh0, aH[mt][0], 0,0,0);
        aH[mt][1] = __builtin_amdgcn_mfma_f32_16x16x32_f16(af[mt][s8], bh1, aH[mt][1], 0,0,0);
      }
    }
    #pragma unroll
    for (int h=0;h<2;h++){
      int nt = nt0+h;
      int n = nt*16 + c16;
      float b1v = b1[n];
      float wv = w2col[n];
      #pragma unroll
      for (int mt=0;mt<2;mt++){
        f32x4 acc = aH[mt][h];
        #pragma unroll
        for (int rr=0;rr<4;rr++){
          float hv = acc[rr]+b1v;
          if (signs){
            unsigned long long m0 = __ballot(hv>0.f);
            if (c16==0) signs[(base+wave*32+mt*16+g*4+rr)*16+nt] = (unsigned short)(m0>>(16*g));
          }
          pacc[mt][rr]=fmaf(fmaxf(hv,0.f),wv,pacc[mt][rr]);
        }
      }
    }
    __syncthreads();
    buf^=1;
  }
  #pragma unroll
  for (int mt=0;mt<2;mt++)
    #pragma unroll
    for (int rr=0;rr<4;rr++){
      float v=pacc[mt][rr];
      v+=__shfl_xor(v,1); v+=__shfl_xor(v,2); v+=__shfl_xor(v,4); v+=__shfl_xor(v,8);
      pacc[mt][rr]=v;
    }
  if (c16==0){
    float bb2=b2[0];
    #pragma unroll
    for (int mt=0;mt<2;mt++)
      #pragma unroll
      for (int rr=0;rr<4;rr++)
        out_sdf[base + wave*32 + mt*16 + g*4 + rr] = pacc[mt][rr] + bb2;
  }
}

// --------- SDF backward via f16 MFMA (nt-pair LDS double buffer; unchanged) ---------
__global__ __launch_bounds__(256) void sdf_bwd_mfma_kernel(
    const float* __restrict__ o, const float* __restrict__ dv, const float* __restrict__ z,
    const float* __restrict__ W0, const float* __restrict__ b0,
    const unsigned short* __restrict__ signs,
    const short* __restrict__ Th,
    const float* __restrict__ w2col,
    float* __restrict__ out_grad)
{
  __shared__ short ldsB[2][8192];
  __shared__ float xs[128][5];
  __shared__ float w0s[3*HH];
  __shared__ float b0s[HH];
  __shared__ _Float16 w2h_s[HH];
  int t = threadIdx.x;
  int base = blockIdx.x*128;
  int wave=t>>6, lane=t&63, g=lane>>4, c16=lane&15;
  for (int i=t;i<3*HH;i+=256) w0s[i]=W0[i];
  b0s[t]=b0[t];
  w2h_s[t]=(_Float16)w2col[t];
  if (t<128){
    float pt[3];
    ZInit zn{0,nullptr,nullptr,0,0,0,0};
    load_point2(o,dv,z,base+t,128,1,ZS,zn,pt,nullptr);
    xs[t][0]=pt[0]; xs[t][1]=pt[1]; xs[t][2]=pt[2];
  }
  {
    const char* gb = (const char*)Th;
    #pragma unroll
    for (int c=0;c<4;c++){
      int ch = wave*4 + c;
      gload_lds16(gb + ch*1024 + lane*16, (void*)&ldsB[0][ch*512]);
    }
  }
  __syncthreads();
  half8v af[2][8];
  #pragma unroll
  for (int mt=0;mt<2;mt++){
    int ptA = base + wave*32 + mt*16 + c16;
    #pragma unroll
    for (int s8=0;s8<8;s8++){
      int j0 = s8*32 + g*8;
      unsigned short wch = signs[ptA*16 + (j0>>4)];
      unsigned bits = ((unsigned)wch >> ((g&1)*8)) & 0xFFu;
      union { _Float16 h[8]; half8v v; } uh;
      #pragma unroll
      for (int jj=0;jj<8;jj++){
        bool on = (bits>>jj)&1u;
        uh.h[jj] = on ? w2h_s[j0+jj] : (_Float16)0.f;
      }
      af[mt][s8]=uh.v;
    }
  }
  float acc3[2][4][3];
  #pragma unroll
  for (int mt=0;mt<2;mt++)
    #pragma unroll
    for (int rr=0;rr<4;rr++){ acc3[mt][rr][0]=0.f; acc3[mt][rr][1]=0.f; acc3[mt][rr][2]=0.f; }
  int buf=0;
  for (int ntp=0;ntp<8;ntp++){
    if (ntp<7){
      const char* gb = (const char*)(Th + 2*(ntp+1)*4096);
      #pragma unroll
      for (int c=0;c<4;c++){
        int ch = wave*4 + c;
        gload_lds16(gb + ch*1024 + lane*16, (void*)&ldsB[buf^1][ch*512]);
      }
    }
    int nt0=2*ntp;
    f32x4 aH[2][2];
    #pragma unroll
    for (int mt=0;mt<2;mt++)
      #pragma unroll
      for (int h=0;h<2;h++) aH[mt][h]=(f32x4){0.f,0.f,0.f,0.f};
    const short* Lb = &ldsB[buf][0];
    #pragma unroll
    for (int s8=0;s8<8;s8++){
      half8v bh0 = *(const half8v*)(Lb + s8*512 + lane*8);
      half8v bh1 = *(const half8v*)(Lb + 4096 + s8*512 + lane*8);
      #pragma unroll
      for (int mt=0;mt<2;mt++){
        aH[mt][0] = __builtin_amdgcn_mfma_f32_16x16x32_f16(af[mt][s8], bh0, aH[mt][0], 0,0,0);
        aH[mt][1] = __builtin_amdgcn_mfma_f32_16x16x32_f16(af[mt][s8], bh1, aH[mt][1], 0,0,0);
      }
    }
    #pragma unroll
    for (int h=0;h<2;h++){
      int nt = nt0+h;
      int tn = nt*16 + c16;
      float w0a=w0s[tn], w0b=w0s[HH+tn], w0c=w0s[2*HH+tn], bb=b0s[tn];
      #pragma unroll
      for (int mt=0;mt<2;mt++){
        f32x4 acc = aH[mt][h];
        #pragma unroll
        for (int rr=0;rr<4;rr++){
          const float* xq = xs[wave*32 + mt*16 + g*4 + rr];
          float h0 = fmaf(xq[0],w0a, fmaf(xq[1],w0b, fmaf(xq[2],w0c, bb)));
          float dh0 = (h0>0.f) ? acc[rr] : 0.f;
          acc3[mt][rr][0]=fmaf(dh0,w0a,acc3[mt][rr][0]);
          acc3[mt][rr][1]=fmaf(dh0,w0b,acc3[mt][rr][1]);
          acc3[mt][rr][2]=fmaf(dh0,w0c,acc3[mt][rr][2]);
        }
      }
    }
    __syncthreads();
    buf^=1;
  }
  #pragma unroll
  for (int mt=0;mt<2;mt++)
    #pragma unroll
    for (int rr=0;rr<4;rr++)
      #pragma unroll
      for (int cc=0;cc<3;cc++){
        float v=acc3[mt][rr][cc];
        v+=__shfl_xor(v,1); v+=__shfl_xor(v,2); v+=__shfl_xor(v,4); v+=__shfl_xor(v,8);
        acc3[mt][rr][cc]=v;
      }
  if (c16==0){
    #pragma unroll
    for (int mt=0;mt<2;mt++)
      #pragma unroll
      for (int rr=0;rr<4;rr++){
        int pt_ = base + wave*32 + mt*16 + g*4 + rr;
        out_grad[pt_*3+0]=acc3[mt][rr][0];
        out_grad[pt_*3+1]=acc3[mt][rr][1];
        out_grad[pt_*3+2]=acc3[mt][rr][2];
      }
  }
}

// --------- batched NeRF MLP: layer-0 via MFMA (A0 in ldsB[1]); rho-packed layer-1 B ---------
__global__ __launch_bounds__(256) void nerf_mfma_batch(
    const float* __restrict__ rO, const float* __restrict__ rD,
    const float* __restrict__ rLo, const float* __restrict__ rHi,
    const float* __restrict__ zbuf, int ptsA, int lgSA, int lgSB, int NRA, int useZ, int midflag,
    const short* __restrict__ A0h, const short* __restrict__ Bh, const float* __restrict__ b1,
    const float* __restrict__ W2, const float* __restrict__ b2,
    float* __restrict__ out_sigma, float* __restrict__ out_rgb)
{
  __shared__ short ldsB[2][8192];
  int t = threadIdx.x;
  int base = blockIdx.x*128;
  int wave=t>>6, lane=t&63, g=lane>>4, c16=lane&15;
  {
    const char* ga = (const char*)A0h;
    const char* gb = (const char*)Bh;
    #pragma unroll
    for (int c=0;c<4;c++){
      int ch = wave*4 + c;
      gload_lds16(ga + ch*1024 + lane*16, (void*)&ldsB[1][ch*512]);
      gload_lds16(gb + ch*1024 + lane*16, (void*)&ldsB[0][ch*512]);
    }
  }
  float xv[2][6];
  #pragma unroll
  for (int mt=0;mt<2;mt++){
    int idx = base + wave*32 + mt*16 + c16;
    int r,i,S;
    if (idx<ptsA){ r=idx>>lgSA; i=idx-(r<<lgSA); S=1<<lgSA; }
    else { int q=idx-ptsA; int rq=q>>lgSB; r=NRA+rq; i=q-(rq<<lgSB); S=1<<lgSB; }
    float zz;
    if (!useZ){
      float a=rLo[r], b=rHi[r];
      zz = a + (b-a)*((float)i/(float)(S-1));
      if (midflag){
        float z1 = a + (b-a)*((float)(i+1)/(float)(S-1));
        zz = (i<S-1)? 0.5f*(zz+z1) : (zz+0.5f*SAMPLE_DIST);
      }
    } else {
      const float* zr = zbuf + r*128;
      zz = zr[i];
      if (midflag) zz = (i<S-1)? 0.5f*(zz+zr[i+1]) : (zz+0.5f*SAMPLE_DIST);
    }
    #pragma unroll
    for (int c=0;c<3;c++){
      float dc=rD[r*3+c];
      xv[mt][c]   = rO[r*3+c] + dc*zz;
      xv[mt][3+c] = dc;
    }
  }
  half8v bx[2];
  #pragma unroll
  for (int mt=0;mt<2;mt++){
    union { _Float16 h[8]; half8v v; } u;
    #pragma unroll
    for (int c=0;c<6;c++) u.h[c]=(_Float16)xv[mt][c];
    u.h[6]=(_Float16)1.f; u.h[7]=(_Float16)0.f;
    bx[mt]=u.v;
  }
  __syncthreads();
  half8v af[2][8];
  #pragma unroll
  for (int s8=0;s8<8;s8++){
    half8v a0a = *(const half8v*)&ldsB[1][(2*s8)*512 + lane*8];
    half8v a0b = *(const half8v*)&ldsB[1][(2*s8+1)*512 + lane*8];
    f32x4 z4 = (f32x4){0.f,0.f,0.f,0.f};
    f32x4 da0 = __builtin_amdgcn_mfma_f32_16x16x32_f16(a0a, bx[0], z4, 0,0,0);
    f32x4 da1 = __builtin_amdgcn_mfma_f32_16x16x32_f16(a0a, bx[1], z4, 0,0,0);
    f32x4 db0 = __builtin_amdgcn_mfma_f32_16x16x32_f16(a0b, bx[0], z4, 0,0,0);
    f32x4 db1 = __builtin_amdgcn_mfma_f32_16x16x32_f16(a0b, bx[1], z4, 0,0,0);
    union { _Float16 h[8]; half8v v; } u0, u1;
    #pragma unroll
    for (int rr=0;rr<4;rr++){
      u0.h[rr]   = (_Float16)fmaxf(da0[rr],0.f);
      u0.h[4+rr] = (_Float16)fmaxf(db0[rr],0.f);
      u1.h[rr]   = (_Float16)fmaxf(da1[rr],0.f);
      u1.h[4+rr] = (_Float16)fmaxf(db1[rr],0.f);
    }
    af[0][s8]=u0.v; af[1][s8]=u1.v;
  }
  __syncthreads();
  float pacc[2][4][4];
  #pragma unroll
  for (int mt=0;mt<2;mt++)
    #pragma unroll
    for (int rr=0;rr<4;rr++){ pacc[mt][rr][0]=0.f; pacc[mt][rr][1]=0.f; pacc[mt][rr][2]=0.f; pacc[mt][rr][3]=0.f; }
  int buf=0;
  for (int ntp=0;ntp<8;ntp++){
    if (ntp<7){
      const char* gb = (const char*)(Bh + 2*(ntp+1)*4096);
      #pragma unroll
      for (int c=0;c<4;c++){
        int ch = wave*4 + c;
        gload_lds16(gb + ch*1024 + lane*16, (void*)&ldsB[buf^1][ch*512]);
      }
    }
    int nt0=2*ntp;
    f32x4 aH[2][2];
    #pragma unroll
    for (int mt=0;mt<2;mt++)
      #pragma unroll
      for (int h=0;h<2;h++) aH[mt][h]=(f32x4){0.f,0.f,0.f,0.f};
    const short* Lb = &ldsB[buf][0];
    #pragma unroll
    for (int s8=0;s8<8;s8++){
      half8v bh0 = *(const half8v*)(Lb + s8*512 + lane*8);
      half8v bh1 = *(const half8v*)(Lb + 4096 + s8*512 + lane*8);
      #pragma unroll
      for (int mt=0;mt<2;mt++){
        aH[mt][0] = __builtin_amdgcn_mfma_f32_16x16x32_f16(af[mt][s8], bh0, aH[mt][0], 0,0,0);
        aH[mt][1] = __builtin_amdgcn_mfma_f32_16x16x32_f16(af[mt][s8], bh1, aH[mt][1], 0,0,0);
      }
    }
    #pragma unroll
    for (int h=0;h<2;h++){
      int nt = nt0+h;
      int n = nt*16 + c16;
      float b1v = b1[n];
      float4 w2v = *(const float4*)(W2 + n*4);
      #pragma unroll
      for (int mt=0;mt<2;mt++){
        f32x4 acc = aH[mt][h];
        #pragma unroll
        for (int rr=0;rr<4;rr++){
          float hh = fmaxf(acc[rr]+b1v, 0.f);
          pacc[mt][rr][0]=fmaf(hh,w2v.x,pacc[mt][rr][0]);
          pacc[mt][rr][1]=fmaf(hh,w2v.y,pacc[mt][rr][1]);
          pacc[mt][rr][2]=fmaf(hh,w2v.z,pacc[mt][rr][2]);
          pacc[mt][rr][3]=fmaf(hh,w2v.w,pacc[mt][rr][3]);
        }
      }
    }
    __syncthreads();
    buf^=1;
  }
  #pragma unroll
  for (int mt=0;mt<2;mt++)
    #pragma unroll
    for (int rr=0;rr<4;rr++)
      #pragma unroll
      for (int c=0;c<4;c++){
        float v=pacc[mt][rr][c];
        v+=__shfl_xor(v,1); v+=__shfl_xor(v,2); v+=__shfl_xor(v,4); v+=__shfl_xor(v,8);
        pacc[mt][rr][c]=v;
      }
  if (c16==0){
    float bb0=b2[0], bb1=b2[1], bb2v=b2[2], bb3=b2[3];
    #pragma unroll
    for (int mt=0;mt<2;mt++)
      #pragma unroll
      for (int rr=0;rr<4;rr++){
        int pt_ = base + wave*32 + mt*16 + g*4 + rr;
        out_sigma[pt_] = pacc[mt][rr][0] + bb0;
        if (out_rgb){
          out_rgb[pt_*3+0] = sigm(pacc[mt][rr][1] + bb1);
          out_rgb[pt_*3+1] = sigm(pacc[mt][rr][2] + bb2v);
          out_rgb[pt_*3+2] = sigm(pacc[mt][rr][3] + bb3);
        }
      }
  }
}

// --------- mask MLPs: two nets 3->256->1, sigmoid ---------
__global__ __launch_bounds__(256) void mask_kernel(
    const float* __restrict__ o, const float* __restrict__ dv, const float* __restrict__ z, int S,
    const float* __restrict__ Wa0, const float* __restrict__ ba0, const float* __restrict__ Wa1, const float* __restrict__ ba1,
    const float* __restrict__ Wb0, const float* __restrict__ bb0, const float* __restrict__ Wb1, const float* __restrict__ bb1,
    float* __restrict__ outA, float* __restrict__ outB)
{
  __shared__ __align__(16) float hA[PP][HH];
  __shared__ float pin[PP][4];
  __shared__ float part[PP][16];
  int t=threadIdx.x;
  int base=blockIdx.x*PP;
  if (t<PP){
    float pt[3];
    load_point(o,dv,z,base+t,S,1,pt,nullptr);
    pin[t][0]=pt[0]; pin[t][1]=pt[1]; pin[t][2]=pt[2];
  }
  __syncthreads();
  {
    float w0=Wa0[t], w1=Wa0[HH+t], w2=Wa0[2*HH+t], bb=ba0[t];
    #pragma unroll
    for (int p=0;p<PP;p++){
      float v = fmaf(pin[p][0],w0, fmaf(pin[p][1],w1, fmaf(pin[p][2],w2, bb)));
      hA[p][t]=fmaxf(v,0.f);
    }
  }
  __syncthreads();
  {
    int p=t>>4, g=t&15;
    float s=0.f;
    #pragma unroll
    for (int m=0;m<16;m++){ int j=g+16*m; s=fmaf(hA[p][j], Wa1[j], s); }
    part[p][g]=s;
  }
  __syncthreads();
  if (t<PP){
    float s=ba1[0];
    #pragma unroll
    for (int g=0;g<16;g++) s+=part[t][g];
    outA[base+t]=sigm(s);
  }
  __syncthreads();
  {
    float w0=Wb0[t], w1=Wb0[HH+t], w2=Wb0[2*HH+t], bb=bb0[t];
    #pragma unroll
    for (int p=0;p<PP;p++){
      float v = fmaf(pin[p][0],w0, fmaf(pin[p][1],w1, fmaf(pin[p][2],w2, bb)));
      hA[p][t]=fmaxf(v,0.f);
    }
  }
  __syncthreads();
  {
    int p=t>>4, g=t&15;
    float s=0.f;
    #pragma unroll
    for (int m=0;m<16;m++){ int j=g+16*m; s=fmaf(hA[p][j], Wb1[j], s); }
    part[p][g]=s;
  }
  __syncthreads();
  if (t<PP){
    float s=bb1[0];
    #pragma unroll
    for (int g=0;g<16;g++) s+=part[t][g];
    outB[base+t]=sigm(s);
  }
}

// --------- SDF up_sample + merge, one wave per ray ---------
__global__ __launch_bounds__(256) void upsample_wave_kernel(float* __restrict__ z,
    const float* __restrict__ sdf, const float* __restrict__ o, const float* __restrict__ dv,
    int S, float s, ZInit zi)
{
  __shared__ float zsh[4][128], ssh[4][128], csh[4][128], nzsh[4][16];
  int wave=threadIdx.x>>6, lane=threadIdx.x&63;
  int r=blockIdx.x*4+wave;
  float* zs=zsh[wave]; float* ss=ssh[wave]; float* cs=csh[wave]; float* nzs=nzsh[wave];
  for (int i=lane;i<S;i+=64){
    float zv;
    if (zi.on){
      float a=zi.loA[r], b=zi.hiA[r];
      zv = a + (b-a)*((float)i/(float)(S-1));
    } else zv = z[r*ZS+i];
    zs[i]=zv; ss[i]=sdf[r*S+i];
  }
  __syncthreads();
  float ox=o[r*3],oy=o[r*3+1],oz=o[r*3+2];
  float dx=dv[r*3],dy=dv[r*3+1],dz=dv[r*3+2];
  int M=S-1;
  auto alpha_at=[&](int k)->float{
    float z0=zs[k], z1=zs[k+1], s0=ss[k], s1=ss[k+1];
    float craw=(s1-s0)/(z1-z0+1e-5f);
    float cprev=(k>0)? (ss[k]-ss[k-1])/(zs[k]-zs[k-1]+1e-5f) : 0.f;
    float cv=fminf(craw,cprev);
    cv=fminf(fmaxf(cv,-1000.f),0.f);
    float px=ox+dx*z0, py=oy+dy*z0, pz=oz+dz*z0;
    float qx=ox+dx*z1, qy=oy+dy*z1, qz=oz+dz*z1;
    float r0=sqrtf(px*px+py*py+pz*pz);
    float r1=sqrtf(qx*qx+qy*qy+qz*qz);
    float inside=(r0<1.f||r1<1.f)?1.f:0.f;
    cv*=inside;
    float mid=0.5f*(s0+s1), dist=z1-z0;
    float pc=sigm((mid-0.5f*cv*dist)*s);
    float nc=sigm((mid+0.5f*cv*dist)*s);
    return (pc-nc+1e-5f)/(pc+1e-5f);
  };
  float al0=(lane<M)? alpha_at(lane):0.f;
  float al1=(lane+64<M)? alpha_at(lane+64):0.f;
  float f0=(lane<M)?(1.f-al0+1e-7f):1.f;
  float f1=(lane+64<M)?(1.f-al1+1e-7f):1.f;
  float ip0=iscan_prod(f0,lane);
  float tt=__shfl_up(ip0,1); float T0=(lane==0)?1.f:tt;
  float tot0=__shfl(ip0,63);
  float ip1=iscan_prod(f1,lane);
  float tu=__shfl_up(ip1,1); float T1=((lane==0)?1.f:tu)*tot0;
  float w0=(lane<M)? al0*T0+1e-5f:0.f;
  float w1=(lane+64<M)? al1*T1+1e-5f:0.f;
  float wsum=wave_sum(w0+w1);
  float inv=1.f/wsum;
  float is0=iscan_sum(w0,lane);
  float st0=__shfl(is0,63);
  float is1=iscan_sum(w1,lane)+st0;
  if (lane<M) cs[lane+1]=is0*inv;
  if (lane+64<M) cs[lane+64+1]=is1*inv;
  if (lane==0) cs[0]=0.f;
  __syncthreads();
  if (lane<16){
    float u=(lane+0.5f)/16.f;
    int lo=0,hi=S;
    while(lo<hi){ int m=(lo+hi)>>1; if(cs[m]<=u) lo=m+1; else hi=m; }
    int below=lo-1; below=below<0?0:(below>S-1?S-1:below);
    int above=lo>S-1?S-1:lo;
    float cb=cs[below], ca=cs[above], bb=zs[below], ba=zs[above];
    float dd=ca-cb; float den=(dd<1e-5f)?1.f:dd;
    nzs[lane]=bb+(u-cb)/den*(ba-bb);
  }
  __syncthreads();
  for (int i=lane;i<S;i+=64){
    float zi_=zs[i]; int cnt=0;
    #pragma unroll
    for (int j=0;j<16;j++) cnt += (nzs[j]<zi_)?1:0;
    z[r*ZS+i+cnt]=zi_;
  }
  if (lane<16){
    float v=nzs[lane]; int rk=0;
    #pragma unroll
    for (int j=0;j<16;j++) rk += ((nzs[j]<v)||(nzs[j]==v&&j<lane))?1:0;
    int lo=0,hi=S;
    while(lo<hi){ int m=(lo+hi)>>1; if(zs[m]<=v) lo=m+1; else hi=m; }
    z[r*ZS+lo+rk]=v;
  }
}

// --------- batched NeRF importance + merge, one wave per ray (4096 rays) ---------
__global__ __launch_bounds__(256) void nerf_imp_batch(float* __restrict__ zbuf,
    const float* __restrict__ sigma, const float* __restrict__ rLo, const float* __restrict__ rHi,
    int ptsA, int NRA)
{
  __shared__ float zsh[4][64], csh[4][64], nzsh[4][64];
  int wave=threadIdx.x>>6, lane=threadIdx.x&63;
  int r=blockIdx.x*4+wave;
  int S = (r<NRA)? 64 : 32;
  int n = S;
  int off = (r<NRA)? r*64 : ptsA + (r-NRA)*32;
  float* zs=zsh[wave]; float* cs=csh[wave]; float* nzs=nzsh[wave];
  if (lane<S){
    float a=rLo[r], b=rHi[r];
    zs[lane]= a + (b-a)*((float)lane/(float)(S-1));
  }
  __syncthreads();
  int M=S-1;
  float al=0.f;
  if (lane<M){
    float d_=zs[lane+1]-zs[lane];
    float sv=sigma[off+lane];
    al=1.f-__expf(-fmaxf(sv,0.f)*d_);
  }
  float f=(lane<M)?(1.f-al+1e-7f):1.f;
  float ip=iscan_prod(f,lane);
  float tt=__shfl_up(ip,1); float T=(lane==0)?1.f:tt;
  float w=(lane<M)? al*T+1e-5f:0.f;
  float wsum=wave_sum(w);
  float inv=1.f/wsum;
  float is=iscan_sum(w,lane);
  if (lane<M) cs[lane+1]=is*inv;
  if (lane==0) cs[0]=0.f;
  __syncthreads();
  if (lane<n){
    float u=(lane+0.5f)/(float)n;
    int lo=0,hi=S;
    while(lo<hi){ int m=(lo+hi)>>1; if(cs[m]<=u) lo=m+1; else hi=m; }
    int below=lo-1; below=below<0?0:(below>S-1?S-1:below);
    int above=lo>S-1?S-1:lo;
    float cb=cs[below], ca=cs[above], bb=zs[below], ba=zs[above];
    float dd=ca-cb; float den=(dd<1e-5f)?1.f:dd;
    nzs[lane]=bb+(u-cb)/den*(ba-bb);
  }
  __syncthreads();
  if (lane<S){
    float zi_=zs[lane]; int cnt=0;
    for (int j=0;j<n;j++) cnt += (nzs[j]<zi_)?1:0;
    zbuf[r*128+lane+cnt]=zi_;
  }
  if (lane<n){
    float v=nzs[lane]; int rk=0;
    for (int j=0;j<n;j++) rk += ((nzs[j]<v)||(nzs[j]==v&&j<lane))?1:0;
    int lo=0,hi=S;
    while(lo<hi){ int m=(lo+hi)>>1; if(zs[m]<=v) lo=m+1; else hi=m; }
    zbuf[r*128+lo+rk]=v;
  }
}

// --------- batched NeRF render, one wave per ray (4096 rays) ---------
__global__ __launch_bounds__(256) void nerf_render_batch(const float* __restrict__ zbuf,
    const float* __restrict__ sigma, const float* __restrict__ rgbp,
    int pts2A, int NRA,
    const float* __restrict__ mva, const float* __restrict__ mvb,
    float* __restrict__ c1b, float* __restrict__ m1b, float* __restrict__ m2b,
    float* __restrict__ cfb, float* __restrict__ czb, float* __restrict__ cbb)
{
  int wave=threadIdx.x>>6, lane=threadIdx.x&63;
  int r=blockIdx.x*4+wave;
  int S = (r<NRA)? 128 : 64;
  int off = (r<NRA)? r*128 : pts2A + (r-NRA)*64;
  const float* zr = zbuf + r*128;
  int domask = (r<1024);
  float a0=0.f,a1=0.f;
  if (lane<S){
    float d_=(lane<S-1)? zr[lane+1]-zr[lane] : SAMPLE_DIST;
    a0=1.f-__expf(-fmaxf(sigma[off+lane],0.f)*d_);
  }
  if (lane+64<S){
    int k=lane+64;
    float d_=(k<S-1)? zr[k+1]-zr[k] : SAMPLE_DIST;
    a1=1.f-__expf(-fmaxf(sigma[off+k],0.f)*d_);
  }
  float f0=(lane<S)?(1.f-a0+1e-7f):1.f;
  float f1=(lane+64<S)?(1.f-a1+1e-7f):1.f;
  float ip0=iscan_prod(f0,lane);
  float tt=__shfl_up(ip0,1); float T0=(lane==0)?1.f:tt;
  float tot0=__shfl(ip0,63);
  float ip1=iscan_prod(f1,lane);
  float tu=__shfl_up(ip1,1); float T1=((lane==0)?1.f:tu)*tot0;
  float w0=(lane<S)? a0*T0:0.f;
  float w1=(lane+64<S)? a1*T1:0.f;
  float c0=0,c1=0,c2=0,m1=0,m2=0;
  if (lane<S){
    int i0=off+lane;
    c0=w0*rgbp[i0*3]; c1=w0*rgbp[i0*3+1]; c2=w0*rgbp[i0*3+2];
    if (domask){ m1=w0*mva[i0]; m2=w0*mvb[i0]; }
  }
  if (lane+64<S){
    int i1=off+lane+64;
    c0=fmaf(w1,rgbp[i1*3],c0); c1=fmaf(w1,rgbp[i1*3+1],c1); c2=fmaf(w1,rgbp[i1*3+2],c2);
    if (domask){ m1=fmaf(w1,mva[i1],m1); m2=fmaf(w1,mvb[i1],m2); }
  }
  c0=wave_sum(c0); c1=wave_sum(c1); c2=wave_sum(c2);
  m1=wave_sum(m1); m2=wave_sum(m2);
  if (lane==0){
    int grp=r>>10, q=r&1023;
    float* outc = (grp==0)? c1b : (grp==1)? cfb : (grp==2)? czb : cbb;
    outc[q*3]=c0; outc[q*3+1]=c1; outc[q*3+2]=c2;
    if (grp==0){ m1b[q]=m1; m2b[q]=m2; }
  }
}

// --------- SDF render + hit/reflect/refract, one wave per ray (S=128) ---------
__global__ __launch_bounds__(256) void sdf_render_hit(const float* __restrict__ z,
    const float* __restrict__ sdf, const float* __restrict__ grad,
    const float* __restrict__ o, const float* __restrict__ dv,
    const float* __restrict__ svar,
    float* __restrict__ hitb, float* __restrict__ reflb, float* __restrict__ refrb)
{
  int wave=threadIdx.x>>6, lane=threadIdx.x&63;
  int r=blockIdx.x*4+wave;
  float inv_s=fminf(fmaxf(__expf(10.f*svar[0]),1e-6f),1e6f);
  float dx=dv[r*3],dy=dv[r*3+1],dz=dv[r*3+2];
  const float* zr=z+r*ZS;
  auto comp=[&](int k, float& alpha, float& midz, float& gx, float& gy, float& gz){
    float d_=(k<127)? zr[k+1]-zr[k] : SAMPLE_DIST;
    midz=zr[k]+0.5f*d_;
    int gi=(r*128+k)*3;
    gx=grad[gi]; gy=grad[gi+1]; gz=grad[gi+2];
    float tc=dx*gx+dy*gy+dz*gz;
    float ic=fminf(tc,0.f);
    float s_=sdf[r*128+k];
    float pc=sigm((s_-0.5f*ic*d_)*inv_s);
    float nc=sigm((s_+0.5f*ic*d_)*inv_s);
    alpha=fminf(fmaxf((pc-nc+1e-5f)/(pc+1e-5f),0.f),1.f);
  };
  float al0,mz0,g0x,g0y,g0z; comp(lane,al0,mz0,g0x,g0y,g0z);
  float al1,mz1,g1x,g1y,g1z; comp(lane+64,al1,mz1,g1x,g1y,g1z);
  float f0=1.f-al0+1e-7f, f1=1.f-al1+1e-7f;
  float ip0=iscan_prod(f0,lane);
  float tt=__shfl_up(ip0,1); float T0=(lane==0)?1.f:tt;
  float tot0=__shfl(ip0,63);
  float ip1=iscan_prod(f1,lane);
  float tu=__shfl_up(ip1,1); float T1=((lane==0)?1.f:tu)*tot0;
  float w0=al0*T0, w1=al1*T1;
  float n0=1.f/(sqrtf(g0x*g0x+g0y*g0y+g0z*g0z)+1e-12f);
  float n1=1.f/(sqrtf(g1x*g1x+g1y*g1y+g1z*g1z)+1e-12f);
  float dep=w0*mz0+w1*mz1;
  float sx=w0*n0*g0x+w1*n1*g1x;
  float sy=w0*n0*g0y+w1*n1*g1y;
  float sz=w0*n0*g0z+w1*n1*g1z;
  dep=wave_sum(dep); sx=wave_sum(sx); sy=wave_sum(sy); sz=wave_sum(sz);
  if (lane==0){
    float nn=1.f/(sqrtf(sx*sx+sy*sy+sz*sz)+1e-12f);
    float nx=sx*nn, ny=sy*nn, nz=sz*nn;
    hitb[r*3]  = o[r*3]  +dx*dep;
    hitb[r*3+1]= o[r*3+1]+dy*dep;
    hitb[r*3+2]= o[r*3+2]+dz*dep;
    float cs=dx*nx+dy*ny+dz*nz;
    if (cs>0.f){ nx=-nx; ny=-ny; nz=-nz; }
    float cosi=-(dx*nx+dy*ny+dz*nz);
    float rx=dx+2.f*cosi*nx, ry=dy+2.f*cosi*ny, rz=dz+2.f*cosi*nz;
    float eta=1.f/1.5f;
    float k=1.f-eta*eta*(1.f-cosi*cosi);
    float sq=sqrtf(fmaxf(k,0.f));
    float tx=eta*dx+(eta*cosi-sq)*nx;
    float ty=eta*dy+(eta*cosi-sq)*ny;
    float tz=eta*dz+(eta*cosi-sq)*nz;
    if (k<0.f){ tx=rx; ty=ry; tz=rz; }
    float rn=1.f/(sqrtf(rx*rx+ry*ry+rz*rz)+1e-12f);
    reflb[r*3]=rx*rn; reflb[r*3+1]=ry*rn; reflb[r*3+2]=rz*rn;
    float tn=1.f/(sqrtf(tx*tx+ty*ty+tz*tz)+1e-12f);
    refrb[r*3]=tx*tn; refrb[r*3+1]=ty*tn; refrb[r*3+2]=tz*tn;
  }
}

// --------- final composition ---------
__global__ void compose_kernel(const float* __restrict__ c1b, const float* __restrict__ m1b,
    const float* __restrict__ m2b, const float* __restrict__ cfb, const float* __restrict__ czb,
    const float* __restrict__ cbb, float* __restrict__ out)
{
  int r = blockIdx.x*blockDim.x + threadIdx.x;
  if (r >= NB) return;
  float m1=m1b[r], m2=m2b[r];
  #pragma unroll
  for (int c=0;c<3;c++){
    float v = c1b[r*3+c]*(1.f-m2) + cfb[r*3+c]*m2;
    float rz = 0.5f*czb[r*3+c] + 0.5f*cbb[r*3+c];
    out[r*3+c] = v*(1.f-m1) + rz*m1;
  }
}

extern "C" void kernel_launch(void* const* d_in, const int* in_sizes, int n_in,
                              void* d_out, int out_size, void* d_ws, size_t ws_size,
                              hipStream_t stream)
{
  const float* rays_o=(const float*)d_in[0];
  const float* rays_d=(const float*)d_in[1];
  const float* nearA =(const float*)d_in[2];
  const float* farA  =(const float*)d_in[3];
  const float* Ws0=(const float*)d_in[4];
  const float* bs0=(const float*)d_in[5];
  const float* Ws1=(const float*)d_in[6];
  const float* bs1=(const float*)d_in[7];
  const float* Ws2=(const float*)d_in[8];
  const float* bs2=(const float*)d_in[9];
  const float* svar=(const float*)d_in[10];
  const float* Wn0=(const float*)d_in[15];
  const float* bn0=(const float*)d_in[16];
  const float* Wn1=(const float*)d_in[17];
  const float* bn1=(const float*)d_in[18];
  const float* Wn2=(const float*)d_in[19];
  const float* bn2=(const float*)d_in[20];
  const float* Wrf0=(const float*)d_in[21];
  const float* brf0=(const float*)d_in[22];
  const float* Wrf1=(const float*)d_in[23];
  const float* brf1=(const float*)d_in[24];
  const float* Wrl0=(const float*)d_in[25];
  const float* brl0=(const float*)d_in[26];
  const float* Wrl1=(const float*)d_in[27];
  const float* brl1=(const float*)d_in[28];

  const int NRA   = 2048;
  const int PTS1A = 2048*64;
  const int PTS2A = 2048*128;

  float* ws=(float*)d_ws;
  float* zbuf = ws;  ws += 4096*128;
  float* sdfb = ws;  ws += 393216;
  float* uni  = ws;  ws += 1441792;
  float* gradb = uni;
  unsigned short* signsb = (unsigned short*)(uni + 393216);
  float* rgbp = uni;
  float* mv1  = ws;  ws += PTS1A;
  float* mv2  = ws;  ws += PTS1A;
  float* W1T  = ws;  ws += HH*HH;
  float* w2c  = ws;  ws += HH;
  float* rO   = ws;  ws += 4096*3;
  float* rD   = ws;  ws += 4096*3;
  float* rLo  = ws;  ws += 4096;
  float* rHi  = ws;  ws += 4096;
  float* hitb = ws;  ws += NB*3;
  float* reflb= ws;  ws += NB*3;
  float* refrb= ws;  ws += NB*3;
  float* c1b  = ws;  ws += NB*3;
  float* m1b  = ws;  ws += NB;
  float* m2b  = ws;  ws += NB;
  float* cfb  = ws;  ws += NB*3;
  float* czb  = ws;  ws += NB*3;
  float* cbb  = ws;  ws += NB*3;
  short* bfragN = (short*)ws; ws += HH*HH/2;
  short* bfragS = (short*)ws; ws += HH*HH/2;
  short* bfragT = (short*)ws; ws += HH*HH/2;
  short* a0N    = (short*)ws; ws += 4096;     // 8192 f16 = 16KB

  const int RB = (NB+255)/256;
  const int WB = NB/4;

  ZInit ziNone{0,nullptr,nullptr,0.f,0.f,0.f,0.f};
  ZInit ziNF  {1,nearA,farA,0.f,0.f,0.f,0.f};

  prep_kernel<<<256,256,0,stream>>>(Ws1, Ws2, W1T, w2c);
  prep_bfrag_rho_kernel<<<256,256,0,stream>>>(Wn1, bfragN);
  prep_bfrag_kernel<<<256,256,0,stream>>>(Ws1, bfragS);
  prep_bfrag_kernel<<<256,256,0,stream>>>(W1T, bfragT);
  prep_a0_kernel<<<32,256,0,stream>>>(Wn0, bn0, a0N, 6);

  // ---- stage 1: importance_sdf (main rays, zbuf stride 128) ----
  for (int i=0;i<4;i++){
    int S=64+16*i;
    float sscale=64.f*(float)(1<<i);
    sdf_mfma_kernel<<<NB*S/128,256,0,stream>>>(rays_o,rays_d,zbuf,S,0,ZS,(i==0?ziNF:ziNone),
        Ws0,bs0, bfragS,bs1, w2c,bs2, sdfb, nullptr);
    upsample_wave_kernel<<<WB,256,0,stream>>>(zbuf,sdfb,rays_o,rays_d,S,sscale,(i==0?ziNF:ziNone));
  }

  // ---- stage 2: render_sdf -> hit/refl/refr ----
  sdf_mfma_kernel<<<NB*128/128,256,0,stream>>>(rays_o,rays_d,zbuf,128,1,ZS,ziNone,
      Ws0,bs0, bfragS,bs1, w2c,bs2, sdfb, signsb);
  sdf_bwd_mfma_kernel<<<NB*128/128,256,0,stream>>>(rays_o,rays_d,zbuf, Ws0,bs0, signsb,
      bfragT, w2c, gradb);
  sdf_render_hit<<<WB,256,0,stream>>>(zbuf,sdfb,gradb,rays_o,rays_d,svar, hitb,reflb,refrb);

  // ---- batched NeRF: build 4096-virtual-ray table ----
  build_rays_kernel<<<16,256,0,stream>>>(rays_o,rays_d,nearA,farA, hitb,reflb,refrb, rO,rD,rLo,rHi);

  // pass 1: eval at analytic z (S=64 for rays<2048, S=32 else) -> sigma only
  nerf_mfma_batch<<<(PTS1A + 2048*32)/128,256,0,stream>>>(rO,rD,rLo,rHi, zbuf,
      PTS1A, 6, 5, NRA, 0, 0,
      a0N, bfragN, bn1, Wn2,bn2, sdfb, nullptr);
  // importance + merge -> zbuf (stride 128)
  nerf_imp_batch<<<4096/4,256,0,stream>>>(zbuf, sdfb, rLo,rHi, PTS1A, NRA);
  // pass 2: eval at midpoints of merged z (S=128 / 64) -> sigma+rgb
  nerf_mfma_batch<<<(PTS2A + 2048*64)/128,256,0,stream>>>(rO,rD,rLo,rHi, zbuf,
      PTS2A, 7, 6, NRA, 1, 1,
      a0N, bfragN, bn1, Wn2,bn2, sdfb,rgbp);
  // masks (main rays only)
  mask_kernel<<<NB*128/PP,256,0,stream>>>(rays_o,rays_d,zbuf,128, Wrf0,brf0,Wrf1,brf1, Wrl0,brl0,Wrl1,brl1, mv1,mv2);
  // render all 4096 rays
  nerf_render_batch<<<4096/4,256,0,stream>>>(zbuf, sdfb, rgbp, PTS2A, NRA, mv1,mv2,
      c1b,m1b,m2b, cfb,czb,cbb);

  // ---- compose ----
  compose_kernel<<<RB,256,0,stream>>>(c1b,m1b,m2b,cfb,czb,cbb,(float*)d_out);
}